// Round 6
// baseline (427.510 us; speedup 1.0000x reference)
//
#include <hip/hip_runtime.h>
#include <hip/hip_bf16.h>
#include <math.h>

#define HIDDEN 2048
#define HARM   64
#define NHEADS 16
#define HDIM   128
#define SEQ    2048
#define BATCH  2
#define ROWS   (BATCH*SEQ)   // 4096
#define RN     (ROWS*HARM)   // 262144 (one K-chunk partial plane)
#define PN     ((size_t)ROWS*HIDDEN)  // 8388608

using bf16x8 = __attribute__((ext_vector_type(8))) short;
using f32x16 = __attribute__((ext_vector_type(16))) float;

// ------------------------------------------- WT[h][o] = amp[o][h] * cos(phase[o][h])
__global__ __launch_bounds__(256) void wt_kernel(
    const float* __restrict__ pq, const float* __restrict__ aq,
    const float* __restrict__ pk, const float* __restrict__ ak,
    const float* __restrict__ pv, const float* __restrict__ av,
    const float* __restrict__ po, const float* __restrict__ ao,
    float* __restrict__ Tq, float* __restrict__ Tk,
    float* __restrict__ Tv, float* __restrict__ To) {
  int i = blockIdx.x * 256 + threadIdx.x;
  const int N = HIDDEN * HARM;
  int set = i / N, j = i - set * N;
  int o = j >> 6, h = j & 63;
  const float* p = (set == 0) ? pq : (set == 1) ? pk : (set == 2) ? pv : po;
  const float* a = (set == 0) ? aq : (set == 1) ? ak : (set == 2) ? av : ao;
  float* T = (set == 0) ? Tq : (set == 1) ? Tk : (set == 2) ? Tv : To;
  T[h * HIDDEN + o] = a[j] * cosf(p[j]);
}

// --------------------------- basis[64][2048] -> BT[2048][64]  (grid 64 x 2 x 4)
__global__ __launch_bounds__(256) void transpose_basis(
    const float* __restrict__ b0, const float* __restrict__ b1,
    const float* __restrict__ b2, const float* __restrict__ b3,
    float* __restrict__ t0, float* __restrict__ t1,
    float* __restrict__ t2, float* __restrict__ t3) {
  const int z = blockIdx.z;
  const float* S = (z == 0) ? b0 : (z == 1) ? b1 : (z == 2) ? b2 : b3;
  float* D = (z == 0) ? t0 : (z == 1) ? t1 : (z == 2) ? t2 : t3;
  const int c0 = blockIdx.x * 32, r0 = blockIdx.y * 32;
  __shared__ float tile[32][33];
  const int t = threadIdx.x;
  const int r = t >> 3, cs = (t & 7) * 4;
  float4 v = *(const float4*)&S[(size_t)(r0 + r) * HIDDEN + c0 + cs];
  tile[r][cs] = v.x; tile[r][cs + 1] = v.y; tile[r][cs + 2] = v.z; tile[r][cs + 3] = v.w;
  __syncthreads();
  float4 o;
  o.x = tile[cs + 0][r]; o.y = tile[cs + 1][r];
  o.z = tile[cs + 2][r]; o.w = tile[cs + 3][r];
  *(float4*)&D[(size_t)(c0 + r) * HARM + r0 + cs] = o;
}

// --------------- split-K resonance: Rp[kc][M][64] += X[M][Kc] * BT[Kc][64]
__global__ __launch_bounds__(256) void resonance_split(
    const float* __restrict__ X,
    const float* __restrict__ B0, const float* __restrict__ B1,
    const float* __restrict__ B2,
    float* __restrict__ R0, float* __restrict__ R1, float* __restrict__ R2) {
  const int z = blockIdx.z;
  const float* BT = (z == 0) ? B0 : (z == 1) ? B1 : B2;
  float* Rp = (z == 0) ? R0 : (z == 1) ? R1 : R2;
  const int row0 = blockIdx.x * 64;
  const int kc = blockIdx.y;
  __shared__ float Xt[32][68];   // [kk][row]
  __shared__ float Bt[32][68];   // [kk][col]
  const int tid = threadIdx.x;
  const int ty = tid >> 4, tx = tid & 15;
  float acc[4][4] = {};
  const int kbase = kc * 512;
  for (int k0 = kbase; k0 < kbase + 512; k0 += 32) {
    #pragma unroll
    for (int i = 0; i < 8; ++i) {
      int idx = tid + i * 256;
      int r = idx >> 5, kk = idx & 31;
      Xt[kk][r] = X[(size_t)(row0 + r) * HIDDEN + k0 + kk];
      int rb = idx & 63, kb = idx >> 6;
      Bt[kb][rb] = BT[(size_t)(k0 + kb) * HARM + rb];
    }
    __syncthreads();
    #pragma unroll
    for (int kk = 0; kk < 32; ++kk) {
      float4 xv = *(const float4*)&Xt[kk][ty * 4];
      float4 bv = *(const float4*)&Bt[kk][tx * 4];
      acc[0][0] += xv.x * bv.x; acc[0][1] += xv.x * bv.y; acc[0][2] += xv.x * bv.z; acc[0][3] += xv.x * bv.w;
      acc[1][0] += xv.y * bv.x; acc[1][1] += xv.y * bv.y; acc[1][2] += xv.y * bv.z; acc[1][3] += xv.y * bv.w;
      acc[2][0] += xv.z * bv.x; acc[2][1] += xv.z * bv.y; acc[2][2] += xv.z * bv.z; acc[2][3] += xv.z * bv.w;
      acc[3][0] += xv.w * bv.x; acc[3][1] += xv.w * bv.y; acc[3][2] += xv.w * bv.z; acc[3][3] += xv.w * bv.w;
    }
    __syncthreads();
  }
  #pragma unroll
  for (int i = 0; i < 4; ++i) {
    float4 v = make_float4(acc[i][0], acc[i][1], acc[i][2], acc[i][3]);
    *(float4*)&Rp[(size_t)(kc * ROWS + row0 + ty * 4 + i) * HARM + tx * 4] = v;
  }
}

// --------------- O-resonance with fused 2-way flash merge in the X staging.
// X := merge(Op[0], Op[1]) via per-(row,head) m/l stats, then Rp = X * BT.
__global__ __launch_bounds__(256) void resonance_merge(
    const float* __restrict__ Op,     // [2][ROWS][HIDDEN] unnormalized O halves
    const float* __restrict__ ML,     // [2][BATCH*NHEADS*SEQ][2] (m, l), float2
    const float* __restrict__ BT,
    float* __restrict__ Rp) {
  const int row0 = blockIdx.x * 64;
  const int kc = blockIdx.y;
  __shared__ float Xt[32][68];
  __shared__ float Bt[32][68];
  const int tid = threadIdx.x;
  const int ty = tid >> 4, tx = tid & 15;
  const size_t HML = (size_t)BATCH * NHEADS * SEQ;
  float acc[4][4] = {};
  const int kbase = kc * 512;
  for (int k0 = kbase; k0 < kbase + 512; k0 += 32) {
    #pragma unroll
    for (int i = 0; i < 8; ++i) {
      int idx = tid + i * 256;
      int r = idx >> 5, kk = idx & 31;
      int row = row0 + r, col = k0 + kk;
      int bb = row >> 11, s = row & 2047, hd = col >> 7;
      size_t mi = ((size_t)(bb * NHEADS + hd)) * SEQ + s;
      float2 ml0 = ((const float2*)ML)[mi];
      float2 ml1 = ((const float2*)ML)[HML + mi];
      float ms = fmaxf(ml0.x, ml1.x);
      float a0 = exp2f(ml0.x - ms), a1 = exp2f(ml1.x - ms);
      float inv = 1.0f / (ml0.y * a0 + ml1.y * a1);
      float v0 = Op[(size_t)row * HIDDEN + col];
      float v1 = Op[PN + (size_t)row * HIDDEN + col];
      Xt[kk][r] = (v0 * a0 + v1 * a1) * inv;
      int rb = idx & 63, kb = idx >> 6;
      Bt[kb][rb] = BT[(size_t)(k0 + kb) * HARM + rb];
    }
    __syncthreads();
    #pragma unroll
    for (int kk = 0; kk < 32; ++kk) {
      float4 xv = *(const float4*)&Xt[kk][ty * 4];
      float4 bv = *(const float4*)&Bt[kk][tx * 4];
      acc[0][0] += xv.x * bv.x; acc[0][1] += xv.x * bv.y; acc[0][2] += xv.x * bv.z; acc[0][3] += xv.x * bv.w;
      acc[1][0] += xv.y * bv.x; acc[1][1] += xv.y * bv.y; acc[1][2] += xv.y * bv.z; acc[1][3] += xv.y * bv.w;
      acc[2][0] += xv.z * bv.x; acc[2][1] += xv.z * bv.y; acc[2][2] += xv.z * bv.z; acc[2][3] += xv.z * bv.w;
      acc[3][0] += xv.w * bv.x; acc[3][1] += xv.w * bv.y; acc[3][2] += xv.w * bv.z; acc[3][3] += xv.w * bv.w;
    }
    __syncthreads();
  }
  #pragma unroll
  for (int i = 0; i < 4; ++i) {
    float4 v = make_float4(acc[i][0], acc[i][1], acc[i][2], acc[i][3]);
    *(float4*)&Rp[(size_t)(kc * ROWS + row0 + ty * 4 + i) * HARM + tx * 4] = v;
  }
}

// --------------- projection: P[M][2048] = (sum_kc Rp[kc]) [M][64] * WT[64][2048]
__global__ __launch_bounds__(256) void proj_bf16_f(
    const float* __restrict__ Rp0, const float* __restrict__ Rp1,
    const float* __restrict__ Rp2,
    const float* __restrict__ T0, const float* __restrict__ T1,
    const float* __restrict__ T2,
    ushort* __restrict__ P0, ushort* __restrict__ P1, ushort* __restrict__ P2) {
  const int z = blockIdx.z;
  const float* Rp = (z == 0) ? Rp0 : (z == 1) ? Rp1 : Rp2;
  const float* WT = (z == 0) ? T0 : (z == 1) ? T1 : T2;
  ushort* P = (z == 0) ? P0 : (z == 1) ? P1 : P2;
  const int row0 = blockIdx.x * 32;
  const int col0 = blockIdx.y * 128;
  __shared__ float Rt[64][36];
  __shared__ float Wt[64][132];
  const int tid = threadIdx.x;
  #pragma unroll
  for (int i = 0; i < 8; ++i) {
    int idx = tid + i * 256;
    int r = idx >> 6, kk = idx & 63;
    size_t o = (size_t)(row0 + r) * HARM + kk;
    Rt[kk][r] = Rp[o] + Rp[RN + o] + Rp[2 * (size_t)RN + o] + Rp[3 * (size_t)RN + o];
  }
  #pragma unroll
  for (int i = 0; i < 32; ++i) {
    int idx = tid + i * 256;
    int c = idx & 127, kk = idx >> 7;
    Wt[kk][c] = WT[(size_t)kk * HIDDEN + col0 + c];
  }
  __syncthreads();
  const int ty = tid >> 5, tx = tid & 31;
  float acc[4][4] = {};
  #pragma unroll
  for (int kk = 0; kk < 64; ++kk) {
    float4 rv = *(const float4*)&Rt[kk][ty * 4];
    float4 wv = *(const float4*)&Wt[kk][tx * 4];
    acc[0][0] += rv.x * wv.x; acc[0][1] += rv.x * wv.y; acc[0][2] += rv.x * wv.z; acc[0][3] += rv.x * wv.w;
    acc[1][0] += rv.y * wv.x; acc[1][1] += rv.y * wv.y; acc[1][2] += rv.y * wv.z; acc[1][3] += rv.y * wv.w;
    acc[2][0] += rv.z * wv.x; acc[2][1] += rv.z * wv.y; acc[2][2] += rv.z * wv.z; acc[2][3] += rv.z * wv.w;
    acc[3][0] += rv.w * wv.x; acc[3][1] += rv.w * wv.y; acc[3][2] += rv.w * wv.z; acc[3][3] += rv.w * wv.w;
  }
  #pragma unroll
  for (int i = 0; i < 4; ++i) {
    union { ushort4 s; __hip_bfloat16 b[4]; } cv;
    cv.b[0] = __float2bfloat16(acc[i][0]); cv.b[1] = __float2bfloat16(acc[i][1]);
    cv.b[2] = __float2bfloat16(acc[i][2]); cv.b[3] = __float2bfloat16(acc[i][3]);
    *(ushort4*)&P[(size_t)(row0 + ty * 4 + i) * HIDDEN + col0 + tx * 4] = cv.s;
  }
}

// fp32-output single variant (final o-projection), grid (128, 16)
__global__ __launch_bounds__(256) void proj_f32(
    const float* __restrict__ Rp, const float* __restrict__ WT,
    float* __restrict__ P) {
  const int row0 = blockIdx.x * 32;
  const int col0 = blockIdx.y * 128;
  __shared__ float Rt[64][36];
  __shared__ float Wt[64][132];
  const int tid = threadIdx.x;
  #pragma unroll
  for (int i = 0; i < 8; ++i) {
    int idx = tid + i * 256;
    int r = idx >> 6, kk = idx & 63;
    size_t o = (size_t)(row0 + r) * HARM + kk;
    Rt[kk][r] = Rp[o] + Rp[RN + o] + Rp[2 * (size_t)RN + o] + Rp[3 * (size_t)RN + o];
  }
  #pragma unroll
  for (int i = 0; i < 32; ++i) {
    int idx = tid + i * 256;
    int c = idx & 127, kk = idx >> 7;
    Wt[kk][c] = WT[(size_t)kk * HIDDEN + col0 + c];
  }
  __syncthreads();
  const int ty = tid >> 5, tx = tid & 31;
  float acc[4][4] = {};
  #pragma unroll
  for (int kk = 0; kk < 64; ++kk) {
    float4 rv = *(const float4*)&Rt[kk][ty * 4];
    float4 wv = *(const float4*)&Wt[kk][tx * 4];
    acc[0][0] += rv.x * wv.x; acc[0][1] += rv.x * wv.y; acc[0][2] += rv.x * wv.z; acc[0][3] += rv.x * wv.w;
    acc[1][0] += rv.y * wv.x; acc[1][1] += rv.y * wv.y; acc[1][2] += rv.y * wv.z; acc[1][3] += rv.y * wv.w;
    acc[2][0] += rv.z * wv.x; acc[2][1] += rv.z * wv.y; acc[2][2] += rv.z * wv.z; acc[2][3] += rv.z * wv.w;
    acc[3][0] += rv.w * wv.x; acc[3][1] += rv.w * wv.y; acc[3][2] += rv.w * wv.z; acc[3][3] += rv.w * wv.w;
  }
  #pragma unroll
  for (int i = 0; i < 4; ++i) {
    float4 v = make_float4(acc[i][0], acc[i][1], acc[i][2], acc[i][3]);
    *(float4*)&P[(size_t)(row0 + ty * 4 + i) * HIDDEN + col0 + tx * 4] = v;
  }
}

// -------------------------------------- per-batch 2048x2048 bf16 transpose (V -> V^T)
__global__ __launch_bounds__(256) void transpose_v(
    const ushort* __restrict__ S, ushort* __restrict__ D) {
  const int b = blockIdx.z;
  const int r0 = blockIdx.y * 32, c0 = blockIdx.x * 32;
  __shared__ ushort tile[32][33];
  const int t = threadIdx.x;
  const int r = t >> 3, cs = (t & 7) * 4;
  const ushort* Sb = S + (size_t)b * SEQ * HIDDEN;
  ushort* Db = D + (size_t)b * SEQ * HIDDEN;
  ushort4 v = *(const ushort4*)&Sb[(size_t)(r0 + r) * HIDDEN + c0 + cs];
  tile[r][cs] = v.x; tile[r][cs + 1] = v.y; tile[r][cs + 2] = v.z; tile[r][cs + 3] = v.w;
  __syncthreads();
  ushort4 o;
  o.x = tile[cs + 0][r]; o.y = tile[cs + 1][r];
  o.z = tile[cs + 2][r]; o.w = tile[cs + 3][r];
  *(ushort4*)&Db[(size_t)(c0 + r) * SEQ + r0 + cs] = o;
}

// ----------------------------------------------------------- MFMA flash attention
// Round-4 body (256 thr, 84 VGPR, 35.8 KB LDS) with keys split 2-way ACROSS
// blocks (blockIdx.z). Grid 1024 -> 3 blocks/CU (reg-limited). Each half writes
// unnormalized O^T + (m,l); the merge is fused into resonance_merge.
#define BQ 128
#define BK 64
#define KSTR 136
#define VSTR 72

__device__ inline unsigned pkbf(float a, float b) {
  __hip_bfloat162 h2 = __float22bfloat162_rn(make_float2(a, b));
  union { __hip_bfloat162 h; unsigned u; } cv; cv.h = h2; return cv.u;
}

__global__ __launch_bounds__(256, 2) void attn_mfma(
    const ushort* __restrict__ Qg, const ushort* __restrict__ Kg,
    const ushort* __restrict__ Vt, float* __restrict__ Op,
    float* __restrict__ ML) {
  __shared__ __align__(16) union SM {
    ushort q[BQ][KSTR];
    struct { ushort k[BK][KSTR]; ushort v[HDIM][VSTR]; } kv;
  } sm;
  const int t = threadIdx.x;
  const int bh = blockIdx.x & 31;
  const int qt = blockIdx.x >> 5;
  const int half = blockIdx.z;
  const int b = bh >> 4, h = bh & 15;
  const int q0 = qt * BQ;
  const int lane = t & 63;
  const int w = t >> 6;
  const int l31 = lane & 31;
  const int hh = lane >> 5;
  const bool hi = (hh != 0);
  const float SC2 = 0.08838834764831845f * 1.4426950408889634f;

  {
    const size_t gbase = ((size_t)(b * SEQ + q0)) * HIDDEN + h * HDIM;
    for (int p = 0; p < 8; ++p) {
      int row = p * 16 + (t >> 4);
      int d0 = (t & 15) * 8;
      uint4 v = *(const uint4*)&Qg[gbase + (size_t)row * HIDDEN + d0];
      *(uint4*)&sm.q[row][d0] = v;
    }
  }
  __syncthreads();
  bf16x8 Qf[8];
  {
    const int qrow = w * 32 + l31;
    #pragma unroll
    for (int ks = 0; ks < 8; ++ks)
      Qf[ks] = *(const bf16x8*)&sm.q[qrow][ks * 16 + 8 * hh];
  }
  __syncthreads();

  float mrow = -1e30f, lsum = 0.0f;
  f32x16 Ot[4];
  #pragma unroll
  for (int i = 0; i < 4; ++i)
    #pragma unroll
    for (int j = 0; j < 16; ++j) Ot[i][j] = 0.0f;

  const int kstart = half * (SEQ / 2);
  for (int ci = 0; ci < 16; ++ci) {
    const int k0 = kstart + ci * BK;
    {
      const size_t gb = ((size_t)(b * SEQ + k0)) * HIDDEN + h * HDIM;
      #pragma unroll
      for (int p = 0; p < 4; ++p) {
        int key = p * 16 + (t >> 4);
        int d0 = (t & 15) * 8;
        uint4 v = *(const uint4*)&Kg[gb + (size_t)key * HIDDEN + d0];
        *(uint4*)&sm.kv.k[key][d0] = v;
      }
      const size_t vb = ((size_t)(b * SEQ + h * HDIM)) * SEQ + k0;
      #pragma unroll
      for (int p = 0; p < 4; ++p) {
        int d = p * 32 + (t >> 3);
        int ks2 = (t & 7) * 8;
        uint4 v = *(const uint4*)&Vt[vb + (size_t)d * SEQ + ks2];
        *(uint4*)&sm.kv.v[d][ks2] = v;
      }
    }
    __syncthreads();

    f32x16 C0, C1;
    #pragma unroll
    for (int j = 0; j < 16; ++j) { C0[j] = 0.0f; C1[j] = 0.0f; }
    #pragma unroll
    for (int ks = 0; ks < 8; ++ks) {
      bf16x8 a0 = *(const bf16x8*)&sm.kv.k[l31][ks * 16 + 8 * hh];
      bf16x8 a1 = *(const bf16x8*)&sm.kv.k[32 + l31][ks * 16 + 8 * hh];
      C0 = __builtin_amdgcn_mfma_f32_32x32x16_bf16(a0, Qf[ks], C0, 0, 0, 0);
      C1 = __builtin_amdgcn_mfma_f32_32x32x16_bf16(a1, Qf[ks], C1, 0, 0, 0);
    }

    float mxr = -1e30f;
    #pragma unroll
    for (int j = 0; j < 16; ++j) mxr = fmaxf(mxr, fmaxf(C0[j], C1[j]));
    mxr = fmaxf(mxr, __shfl_xor(mxr, 32));
    const float mnew = fmaxf(mrow, mxr * SC2);
    const float alpha = exp2f(mrow - mnew);
    float ssum = 0.0f;
    #pragma unroll
    for (int j = 0; j < 16; ++j) {
      float e0 = exp2f(fmaf(C0[j], SC2, -mnew));
      float e1 = exp2f(fmaf(C1[j], SC2, -mnew));
      C0[j] = e0; C1[j] = e1;
      ssum += e0 + e1;
    }
    ssum += __shfl_xor(ssum, 32);
    lsum = lsum * alpha + ssum;
    mrow = mnew;
    #pragma unroll
    for (int i = 0; i < 4; ++i)
      #pragma unroll
      for (int j = 0; j < 16; ++j) Ot[i][j] *= alpha;

    #pragma unroll
    for (int st = 0; st < 4; ++st) {
      const int eb = 8 * (st & 1);
      float o0, o1, o2, o3, g0, g1, g2, g3;
      if (st < 2) {
        o0 = hi ? C0[eb + 4] : C0[eb + 0]; o1 = hi ? C0[eb + 5] : C0[eb + 1];
        o2 = hi ? C0[eb + 6] : C0[eb + 2]; o3 = hi ? C0[eb + 7] : C0[eb + 3];
        g0 = hi ? C0[eb + 0] : C0[eb + 4]; g1 = hi ? C0[eb + 1] : C0[eb + 5];
        g2 = hi ? C0[eb + 2] : C0[eb + 6]; g3 = hi ? C0[eb + 3] : C0[eb + 7];
      } else {
        o0 = hi ? C1[eb + 4] : C1[eb + 0]; o1 = hi ? C1[eb + 5] : C1[eb + 1];
        o2 = hi ? C1[eb + 6] : C1[eb + 2]; o3 = hi ? C1[eb + 7] : C1[eb + 3];
        g0 = hi ? C1[eb + 0] : C1[eb + 4]; g1 = hi ? C1[eb + 1] : C1[eb + 5];
        g2 = hi ? C1[eb + 2] : C1[eb + 6]; g3 = hi ? C1[eb + 3] : C1[eb + 7];
      }
      unsigned so0 = pkbf(o0, o1), so1 = pkbf(o2, o3);
      unsigned sp0 = pkbf(g0, g1), sp1 = pkbf(g2, g3);
      unsigned r0 = (unsigned)__shfl_xor((int)sp0, 32);
      unsigned r1 = (unsigned)__shfl_xor((int)sp1, 32);
      union { unsigned u[4]; bf16x8 v; } cv;
      cv.u[0] = hi ? r0 : so0;
      cv.u[1] = hi ? r1 : so1;
      cv.u[2] = hi ? so0 : r0;
      cv.u[3] = hi ? so1 : r1;
      #pragma unroll
      for (int mt = 0; mt < 4; ++mt) {
        bf16x8 a2 = *(const bf16x8*)&sm.kv.v[mt * 32 + l31][st * 16 + 8 * hh];
        Ot[mt] = __builtin_amdgcn_mfma_f32_32x32x16_bf16(a2, cv.v, Ot[mt], 0, 0, 0);
      }
    }
    __syncthreads();
  }

  // ---- epilogue: store UNNORMALIZED O^T partial + (m, l)
  const int qrow = q0 + w * 32 + l31;
  float* ob = Op + (size_t)half * PN +
              ((size_t)(b * SEQ + qrow)) * HIDDEN + h * HDIM;
  #pragma unroll
  for (int mt = 0; mt < 4; ++mt)
    #pragma unroll
    for (int g = 0; g < 4; ++g) {
      float4 vv = make_float4(Ot[mt][4 * g + 0], Ot[mt][4 * g + 1],
                              Ot[mt][4 * g + 2], Ot[mt][4 * g + 3]);
      *(float4*)&ob[mt * 32 + 8 * g + 4 * hh] = vv;
    }
  if (hh == 0) {
    size_t mi = (size_t)half * BATCH * NHEADS * SEQ +
                ((size_t)(b * NHEADS + h)) * SEQ + qrow;
    ((float2*)ML)[mi] = make_float2(mrow, lsum);
  }
}

// -------------------------------------------------------------------------- launcher
extern "C" void kernel_launch(void* const* d_in, const int* in_sizes, int n_in,
                              void* d_out, int out_size, void* d_ws, size_t ws_size,
                              hipStream_t stream) {
  (void)in_sizes; (void)n_in; (void)out_size; (void)ws_size;
  const float* X       = (const float*)d_in[0];
  const float* basis_q = (const float*)d_in[1];
  const float* phase_q = (const float*)d_in[2];
  const float* amp_q   = (const float*)d_in[3];
  const float* basis_k = (const float*)d_in[4];
  const float* phase_k = (const float*)d_in[5];
  const float* amp_k   = (const float*)d_in[6];
  const float* basis_v = (const float*)d_in[7];
  const float* phase_v = (const float*)d_in[8];
  const float* amp_v   = (const float*)d_in[9];
  const float* basis_o = (const float*)d_in[10];
  const float* phase_o = (const float*)d_in[11];
  const float* amp_o   = (const float*)d_in[12];

  const size_t WN = (size_t)HIDDEN * HARM;   // 131072

  char* p = (char*)d_ws;
  float* WTq = (float*)p; p += WN * 4;
  float* WTk = (float*)p; p += WN * 4;
  float* WTv = (float*)p; p += WN * 4;
  float* WTo = (float*)p; p += WN * 4;
  float* BTq = (float*)p; p += WN * 4;
  float* BTk = (float*)p; p += WN * 4;
  float* BTv = (float*)p; p += WN * 4;
  float* BTo = (float*)p; p += WN * 4;
  float* Rqp = (float*)p; p += (size_t)4 * RN * 4;
  float* Rkp = (float*)p; p += (size_t)4 * RN * 4;
  float* Rvp = (float*)p; p += (size_t)4 * RN * 4;
  float* Rop = (float*)p; p += (size_t)4 * RN * 4;
  __hip_bfloat16* Qb = (__hip_bfloat16*)p; p += PN * 2;
  __hip_bfloat16* Kb = (__hip_bfloat16*)p; p += PN * 2;
  __hip_bfloat16* Vb = (__hip_bfloat16*)p; p += PN * 2;
  __hip_bfloat16* VtB = (__hip_bfloat16*)p; p += PN * 2;
  float* Opart = (float*)p; p += (size_t)2 * PN * 4;  // two unnormalized halves
  float* MLb   = (float*)p; p += (size_t)2 * BATCH * NHEADS * SEQ * 2 * 4;
  float* out = (float*)d_out;

  wt_kernel<<<2048, 256, 0, stream>>>(phase_q, amp_q, phase_k, amp_k,
                                      phase_v, amp_v, phase_o, amp_o,
                                      WTq, WTk, WTv, WTo);
  transpose_basis<<<dim3(64, 2, 4), 256, 0, stream>>>(
      basis_q, basis_k, basis_v, basis_o, BTq, BTk, BTv, BTo);

  resonance_split<<<dim3(64, 4, 3), 256, 0, stream>>>(
      X, BTq, BTk, BTv, Rqp, Rkp, Rvp);

  proj_bf16_f<<<dim3(128, 16, 3), 256, 0, stream>>>(
      Rqp, Rkp, Rvp, WTq, WTk, WTv,
      (ushort*)Qb, (ushort*)Kb, (ushort*)Vb);

  transpose_v<<<dim3(HIDDEN / 32, SEQ / 32, BATCH), 256, 0, stream>>>(
      (const ushort*)Vb, (ushort*)VtB);

  attn_mfma<<<dim3((SEQ / BQ) * 32, 1, 2), 256, 0, stream>>>(
      (const ushort*)Qb, (const ushort*)Kb, (const ushort*)VtB, Opart, MLb);

  resonance_merge<<<dim3(64, 4), 256, 0, stream>>>(Opart, MLb, BTo, Rop);

  proj_f32<<<dim3(128, 16), 256, 0, stream>>>(Rop, WTo, out);
}

// Round 7
// 366.375 us; speedup vs baseline: 1.1669x; 1.1669x over previous
//
#include <hip/hip_runtime.h>
#include <hip/hip_bf16.h>
#include <math.h>

#define HIDDEN 2048
#define HARM   64
#define NHEADS 16
#define HDIM   128
#define SEQ    2048
#define BATCH  2
#define ROWS   (BATCH*SEQ)   // 4096
#define RN     (ROWS*HARM)   // 262144 (one K-chunk partial plane)
#define PN     ((size_t)ROWS*HIDDEN)  // 8388608

using bf16x8 = __attribute__((ext_vector_type(8))) short;
using f32x16 = __attribute__((ext_vector_type(16))) float;

// ------------------------------------------- WT[h][o] = amp[o][h] * cos(phase[o][h])
__global__ __launch_bounds__(256) void wt_kernel(
    const float* __restrict__ pq, const float* __restrict__ aq,
    const float* __restrict__ pk, const float* __restrict__ ak,
    const float* __restrict__ pv, const float* __restrict__ av,
    const float* __restrict__ po, const float* __restrict__ ao,
    float* __restrict__ Tq, float* __restrict__ Tk,
    float* __restrict__ Tv, float* __restrict__ To) {
  int i = blockIdx.x * 256 + threadIdx.x;
  const int N = HIDDEN * HARM;
  int set = i / N, j = i - set * N;
  int o = j >> 6, h = j & 63;
  const float* p = (set == 0) ? pq : (set == 1) ? pk : (set == 2) ? pv : po;
  const float* a = (set == 0) ? aq : (set == 1) ? ak : (set == 2) ? av : ao;
  float* T = (set == 0) ? Tq : (set == 1) ? Tk : (set == 2) ? Tv : To;
  T[h * HIDDEN + o] = a[j] * cosf(p[j]);
}

// --------------------------- basis[64][2048] -> BT[2048][64]  (grid 64 x 2 x 4)
__global__ __launch_bounds__(256) void transpose_basis(
    const float* __restrict__ b0, const float* __restrict__ b1,
    const float* __restrict__ b2, const float* __restrict__ b3,
    float* __restrict__ t0, float* __restrict__ t1,
    float* __restrict__ t2, float* __restrict__ t3) {
  const int z = blockIdx.z;
  const float* S = (z == 0) ? b0 : (z == 1) ? b1 : (z == 2) ? b2 : b3;
  float* D = (z == 0) ? t0 : (z == 1) ? t1 : (z == 2) ? t2 : t3;
  const int c0 = blockIdx.x * 32, r0 = blockIdx.y * 32;
  __shared__ float tile[32][33];
  const int t = threadIdx.x;
  const int r = t >> 3, cs = (t & 7) * 4;
  float4 v = *(const float4*)&S[(size_t)(r0 + r) * HIDDEN + c0 + cs];
  tile[r][cs] = v.x; tile[r][cs + 1] = v.y; tile[r][cs + 2] = v.z; tile[r][cs + 3] = v.w;
  __syncthreads();
  float4 o;
  o.x = tile[cs + 0][r]; o.y = tile[cs + 1][r];
  o.z = tile[cs + 2][r]; o.w = tile[cs + 3][r];
  *(float4*)&D[(size_t)(c0 + r) * HARM + r0 + cs] = o;
}

// --------------- split-K resonance: Rp[kc][M][64] += X[M][Kc] * BT[Kc][64]
__global__ __launch_bounds__(256) void resonance_split(
    const float* __restrict__ X,
    const float* __restrict__ B0, const float* __restrict__ B1,
    const float* __restrict__ B2,
    float* __restrict__ R0, float* __restrict__ R1, float* __restrict__ R2) {
  const int z = blockIdx.z;
  const float* BT = (z == 0) ? B0 : (z == 1) ? B1 : B2;
  float* Rp = (z == 0) ? R0 : (z == 1) ? R1 : R2;
  const int row0 = blockIdx.x * 64;
  const int kc = blockIdx.y;
  __shared__ float Xt[32][68];   // [kk][row]
  __shared__ float Bt[32][68];   // [kk][col]
  const int tid = threadIdx.x;
  const int ty = tid >> 4, tx = tid & 15;
  float acc[4][4] = {};
  const int kbase = kc * 512;
  for (int k0 = kbase; k0 < kbase + 512; k0 += 32) {
    #pragma unroll
    for (int i = 0; i < 8; ++i) {
      int idx = tid + i * 256;
      int r = idx >> 5, kk = idx & 31;
      Xt[kk][r] = X[(size_t)(row0 + r) * HIDDEN + k0 + kk];
      int rb = idx & 63, kb = idx >> 6;
      Bt[kb][rb] = BT[(size_t)(k0 + kb) * HARM + rb];
    }
    __syncthreads();
    #pragma unroll
    for (int kk = 0; kk < 32; ++kk) {
      float4 xv = *(const float4*)&Xt[kk][ty * 4];
      float4 bv = *(const float4*)&Bt[kk][tx * 4];
      acc[0][0] += xv.x * bv.x; acc[0][1] += xv.x * bv.y; acc[0][2] += xv.x * bv.z; acc[0][3] += xv.x * bv.w;
      acc[1][0] += xv.y * bv.x; acc[1][1] += xv.y * bv.y; acc[1][2] += xv.y * bv.z; acc[1][3] += xv.y * bv.w;
      acc[2][0] += xv.z * bv.x; acc[2][1] += xv.z * bv.y; acc[2][2] += xv.z * bv.z; acc[2][3] += xv.z * bv.w;
      acc[3][0] += xv.w * bv.x; acc[3][1] += xv.w * bv.y; acc[3][2] += xv.w * bv.z; acc[3][3] += xv.w * bv.w;
    }
    __syncthreads();
  }
  #pragma unroll
  for (int i = 0; i < 4; ++i) {
    float4 v = make_float4(acc[i][0], acc[i][1], acc[i][2], acc[i][3]);
    *(float4*)&Rp[(size_t)(kc * ROWS + row0 + ty * 4 + i) * HARM + tx * 4] = v;
  }
}

// --------------- projection: P[M][2048] = (sum_kc Rp[kc]) [M][64] * WT[64][2048]
__global__ __launch_bounds__(256) void proj_bf16_f(
    const float* __restrict__ Rp0, const float* __restrict__ Rp1,
    const float* __restrict__ Rp2,
    const float* __restrict__ T0, const float* __restrict__ T1,
    const float* __restrict__ T2,
    ushort* __restrict__ P0, ushort* __restrict__ P1, ushort* __restrict__ P2) {
  const int z = blockIdx.z;
  const float* Rp = (z == 0) ? Rp0 : (z == 1) ? Rp1 : Rp2;
  const float* WT = (z == 0) ? T0 : (z == 1) ? T1 : T2;
  ushort* P = (z == 0) ? P0 : (z == 1) ? P1 : P2;
  const int row0 = blockIdx.x * 32;
  const int col0 = blockIdx.y * 128;
  __shared__ float Rt[64][36];
  __shared__ float Wt[64][132];
  const int tid = threadIdx.x;
  #pragma unroll
  for (int i = 0; i < 8; ++i) {
    int idx = tid + i * 256;
    int r = idx >> 6, kk = idx & 63;
    size_t o = (size_t)(row0 + r) * HARM + kk;
    Rt[kk][r] = Rp[o] + Rp[RN + o] + Rp[2 * (size_t)RN + o] + Rp[3 * (size_t)RN + o];
  }
  #pragma unroll
  for (int i = 0; i < 32; ++i) {
    int idx = tid + i * 256;
    int c = idx & 127, kk = idx >> 7;
    Wt[kk][c] = WT[(size_t)kk * HIDDEN + col0 + c];
  }
  __syncthreads();
  const int ty = tid >> 5, tx = tid & 31;
  float acc[4][4] = {};
  #pragma unroll
  for (int kk = 0; kk < 64; ++kk) {
    float4 rv = *(const float4*)&Rt[kk][ty * 4];
    float4 wv = *(const float4*)&Wt[kk][tx * 4];
    acc[0][0] += rv.x * wv.x; acc[0][1] += rv.x * wv.y; acc[0][2] += rv.x * wv.z; acc[0][3] += rv.x * wv.w;
    acc[1][0] += rv.y * wv.x; acc[1][1] += rv.y * wv.y; acc[1][2] += rv.y * wv.z; acc[1][3] += rv.y * wv.w;
    acc[2][0] += rv.z * wv.x; acc[2][1] += rv.z * wv.y; acc[2][2] += rv.z * wv.z; acc[2][3] += rv.z * wv.w;
    acc[3][0] += rv.w * wv.x; acc[3][1] += rv.w * wv.y; acc[3][2] += rv.w * wv.z; acc[3][3] += rv.w * wv.w;
  }
  #pragma unroll
  for (int i = 0; i < 4; ++i) {
    union { ushort4 s; __hip_bfloat16 b[4]; } cv;
    cv.b[0] = __float2bfloat16(acc[i][0]); cv.b[1] = __float2bfloat16(acc[i][1]);
    cv.b[2] = __float2bfloat16(acc[i][2]); cv.b[3] = __float2bfloat16(acc[i][3]);
    *(ushort4*)&P[(size_t)(row0 + ty * 4 + i) * HIDDEN + col0 + tx * 4] = cv.s;
  }
}

// fp32-output single variant (final o-projection), grid (128, 16)
__global__ __launch_bounds__(256) void proj_f32(
    const float* __restrict__ Rp, const float* __restrict__ WT,
    float* __restrict__ P) {
  const int row0 = blockIdx.x * 32;
  const int col0 = blockIdx.y * 128;
  __shared__ float Rt[64][36];
  __shared__ float Wt[64][132];
  const int tid = threadIdx.x;
  #pragma unroll
  for (int i = 0; i < 8; ++i) {
    int idx = tid + i * 256;
    int r = idx >> 6, kk = idx & 63;
    size_t o = (size_t)(row0 + r) * HARM + kk;
    Rt[kk][r] = Rp[o] + Rp[RN + o] + Rp[2 * (size_t)RN + o] + Rp[3 * (size_t)RN + o];
  }
  #pragma unroll
  for (int i = 0; i < 32; ++i) {
    int idx = tid + i * 256;
    int c = idx & 127, kk = idx >> 7;
    Wt[kk][c] = WT[(size_t)kk * HIDDEN + col0 + c];
  }
  __syncthreads();
  const int ty = tid >> 5, tx = tid & 31;
  float acc[4][4] = {};
  #pragma unroll
  for (int kk = 0; kk < 64; ++kk) {
    float4 rv = *(const float4*)&Rt[kk][ty * 4];
    float4 wv = *(const float4*)&Wt[kk][tx * 4];
    acc[0][0] += rv.x * wv.x; acc[0][1] += rv.x * wv.y; acc[0][2] += rv.x * wv.z; acc[0][3] += rv.x * wv.w;
    acc[1][0] += rv.y * wv.x; acc[1][1] += rv.y * wv.y; acc[1][2] += rv.y * wv.z; acc[1][3] += rv.y * wv.w;
    acc[2][0] += rv.z * wv.x; acc[2][1] += rv.z * wv.y; acc[2][2] += rv.z * wv.z; acc[2][3] += rv.z * wv.w;
    acc[3][0] += rv.w * wv.x; acc[3][1] += rv.w * wv.y; acc[3][2] += rv.w * wv.z; acc[3][3] += rv.w * wv.w;
  }
  #pragma unroll
  for (int i = 0; i < 4; ++i) {
    float4 v = make_float4(acc[i][0], acc[i][1], acc[i][2], acc[i][3]);
    *(float4*)&P[(size_t)(row0 + ty * 4 + i) * HIDDEN + col0 + tx * 4] = v;
  }
}

// -------------------------------------- per-batch 2048x2048 bf16 transpose (V -> V^T)
__global__ __launch_bounds__(256) void transpose_v(
    const ushort* __restrict__ S, ushort* __restrict__ D) {
  const int b = blockIdx.z;
  const int r0 = blockIdx.y * 32, c0 = blockIdx.x * 32;
  __shared__ ushort tile[32][33];
  const int t = threadIdx.x;
  const int r = t >> 3, cs = (t & 7) * 4;
  const ushort* Sb = S + (size_t)b * SEQ * HIDDEN;
  ushort* Db = D + (size_t)b * SEQ * HIDDEN;
  ushort4 v = *(const ushort4*)&Sb[(size_t)(r0 + r) * HIDDEN + c0 + cs];
  tile[r][cs] = v.x; tile[r][cs + 1] = v.y; tile[r][cs + 2] = v.z; tile[r][cs + 3] = v.w;
  __syncthreads();
  ushort4 o;
  o.x = tile[cs + 0][r]; o.y = tile[cs + 1][r];
  o.z = tile[cs + 2][r]; o.w = tile[cs + 3][r];
  *(ushort4*)&Db[(size_t)(c0 + r) * SEQ + r0 + cs] = o;
}

// ----------------------------------------------------------- MFMA flash attention
// R4 body + software-pipelined KV staging: double-buffered KV LDS; global loads
// for chunk i+1 issue BEFORE computing chunk i, so the barrier's vmcnt drain
// waits on loads that completed during compute (was: full HBM latency exposed).
#define BQ 128
#define BK 64
#define KSTR 136
#define VSTR 72

__device__ inline unsigned pkbf(float a, float b) {
  __hip_bfloat162 h2 = __float22bfloat162_rn(make_float2(a, b));
  union { __hip_bfloat162 h; unsigned u; } cv; cv.h = h2; return cv.u;
}

__global__ __launch_bounds__(256, 2) void attn_mfma(
    const ushort* __restrict__ Qg, const ushort* __restrict__ Kg,
    const ushort* __restrict__ Vt, float* __restrict__ O) {
  __shared__ __align__(16) union SM {
    ushort q[BQ][KSTR];                                        // 34816 B
    struct { ushort k[BK][KSTR]; ushort v[HDIM][VSTR]; } kv[2]; // 71680 B
  } sm;
  const int t = threadIdx.x;
  const int bh = blockIdx.x & 31;
  const int qt = blockIdx.x >> 5;
  const int b = bh >> 4, h = bh & 15;
  const int q0 = qt * BQ;
  const int lane = t & 63;
  const int w = t >> 6;
  const int l31 = lane & 31;
  const int hh = lane >> 5;
  const bool hi = (hh != 0);
  const float SC2 = 0.08838834764831845f * 1.4426950408889634f;

  // per-thread staging coordinates
  const int sk_key = t >> 4;            // 0..15 (+p*16)
  const int sk_d0 = (t & 15) * 8;
  const int sv_d = t >> 3;              // 0..31 (+p*32)
  const int sv_k = (t & 7) * 8;
  const size_t kbase = ((size_t)(b * SEQ)) * HIDDEN + h * HDIM;
  const size_t vbase = ((size_t)(b * SEQ + h * HDIM)) * SEQ;

  // ---- stage Q tile, pull B-fragments into registers
  {
    const size_t gbase = ((size_t)(b * SEQ + q0)) * HIDDEN + h * HDIM;
    for (int p = 0; p < 8; ++p) {
      int row = p * 16 + sk_key;
      uint4 v = *(const uint4*)&Qg[gbase + (size_t)row * HIDDEN + sk_d0];
      *(uint4*)&sm.q[row][sk_d0] = v;
    }
  }
  __syncthreads();
  bf16x8 Qf[8];
  {
    const int qrow = w * 32 + l31;
    #pragma unroll
    for (int ks = 0; ks < 8; ++ks)
      Qf[ks] = *(const bf16x8*)&sm.q[qrow][ks * 16 + 8 * hh];
  }
  __syncthreads();

  float mrow = -1e30f, lsum = 0.0f;
  f32x16 Ot[4];
  #pragma unroll
  for (int i = 0; i < 4; ++i)
    #pragma unroll
    for (int j = 0; j < 16; ++j) Ot[i][j] = 0.0f;

  uint4 kp[4], vp[4];
  // ---- prologue: load + store chunk 0 into buffer 0
  {
    const size_t gb = kbase + (size_t)0 * HIDDEN;
    #pragma unroll
    for (int p = 0; p < 4; ++p)
      kp[p] = *(const uint4*)&Kg[gb + (size_t)(p * 16 + sk_key) * HIDDEN + sk_d0];
    #pragma unroll
    for (int p = 0; p < 4; ++p)
      vp[p] = *(const uint4*)&Vt[vbase + (size_t)(p * 32 + sv_d) * SEQ + sv_k];
    #pragma unroll
    for (int p = 0; p < 4; ++p)
      *(uint4*)&sm.kv[0].k[p * 16 + sk_key][sk_d0] = kp[p];
    #pragma unroll
    for (int p = 0; p < 4; ++p)
      *(uint4*)&sm.kv[0].v[p * 32 + sv_d][sv_k] = vp[p];
  }
  __syncthreads();

  for (int ci = 0; ci < 32; ++ci) {
    // ---- issue prefetch for next chunk (clamped; chunk 31 reloads itself)
    {
      const int cn = (ci < 31) ? ci + 1 : 31;
      const size_t gb = kbase + (size_t)(cn * BK) * HIDDEN;
      #pragma unroll
      for (int p = 0; p < 4; ++p)
        kp[p] = *(const uint4*)&Kg[gb + (size_t)(p * 16 + sk_key) * HIDDEN + sk_d0];
      const size_t vb = vbase + cn * BK;
      #pragma unroll
      for (int p = 0; p < 4; ++p)
        vp[p] = *(const uint4*)&Vt[vb + (size_t)(p * 32 + sv_d) * SEQ + sv_k];
    }
    const int cb = ci & 1;

    // ---- S^T = K . Q^T
    f32x16 C0, C1;
    #pragma unroll
    for (int j = 0; j < 16; ++j) { C0[j] = 0.0f; C1[j] = 0.0f; }
    #pragma unroll
    for (int ks = 0; ks < 8; ++ks) {
      bf16x8 a0 = *(const bf16x8*)&sm.kv[cb].k[l31][ks * 16 + 8 * hh];
      bf16x8 a1 = *(const bf16x8*)&sm.kv[cb].k[32 + l31][ks * 16 + 8 * hh];
      C0 = __builtin_amdgcn_mfma_f32_32x32x16_bf16(a0, Qf[ks], C0, 0, 0, 0);
      C1 = __builtin_amdgcn_mfma_f32_32x32x16_bf16(a1, Qf[ks], C1, 0, 0, 0);
    }

    // ---- online softmax
    float mxr = -1e30f;
    #pragma unroll
    for (int j = 0; j < 16; ++j) mxr = fmaxf(mxr, fmaxf(C0[j], C1[j]));
    mxr = fmaxf(mxr, __shfl_xor(mxr, 32));
    const float mnew = fmaxf(mrow, mxr * SC2);
    const float alpha = exp2f(mrow - mnew);
    float ssum = 0.0f;
    #pragma unroll
    for (int j = 0; j < 16; ++j) {
      float e0 = exp2f(fmaf(C0[j], SC2, -mnew));
      float e1 = exp2f(fmaf(C1[j], SC2, -mnew));
      C0[j] = e0; C1[j] = e1;
      ssum += e0 + e1;
    }
    ssum += __shfl_xor(ssum, 32);
    lsum = lsum * alpha + ssum;
    mrow = mnew;
    #pragma unroll
    for (int i = 0; i < 4; ++i)
      #pragma unroll
      for (int j = 0; j < 16; ++j) Ot[i][j] *= alpha;

    // ---- O^T += V^T . P^T
    #pragma unroll
    for (int st = 0; st < 4; ++st) {
      const int eb = 8 * (st & 1);
      float o0, o1, o2, o3, g0, g1, g2, g3;
      if (st < 2) {
        o0 = hi ? C0[eb + 4] : C0[eb + 0]; o1 = hi ? C0[eb + 5] : C0[eb + 1];
        o2 = hi ? C0[eb + 6] : C0[eb + 2]; o3 = hi ? C0[eb + 7] : C0[eb + 3];
        g0 = hi ? C0[eb + 0] : C0[eb + 4]; g1 = hi ? C0[eb + 1] : C0[eb + 5];
        g2 = hi ? C0[eb + 2] : C0[eb + 6]; g3 = hi ? C0[eb + 3] : C0[eb + 7];
      } else {
        o0 = hi ? C1[eb + 4] : C1[eb + 0]; o1 = hi ? C1[eb + 5] : C1[eb + 1];
        o2 = hi ? C1[eb + 6] : C1[eb + 2]; o3 = hi ? C1[eb + 7] : C1[eb + 3];
        g0 = hi ? C1[eb + 0] : C1[eb + 4]; g1 = hi ? C1[eb + 1] : C1[eb + 5];
        g2 = hi ? C1[eb + 2] : C1[eb + 6]; g3 = hi ? C1[eb + 3] : C1[eb + 7];
      }
      unsigned so0 = pkbf(o0, o1), so1 = pkbf(o2, o3);
      unsigned sp0 = pkbf(g0, g1), sp1 = pkbf(g2, g3);
      unsigned r0 = (unsigned)__shfl_xor((int)sp0, 32);
      unsigned r1 = (unsigned)__shfl_xor((int)sp1, 32);
      union { unsigned u[4]; bf16x8 v; } cv;
      cv.u[0] = hi ? r0 : so0;
      cv.u[1] = hi ? r1 : so1;
      cv.u[2] = hi ? so0 : r0;
      cv.u[3] = hi ? so1 : r1;
      #pragma unroll
      for (int mt = 0; mt < 4; ++mt) {
        bf16x8 a2 = *(const bf16x8*)&sm.kv[cb].v[mt * 32 + l31][st * 16 + 8 * hh];
        Ot[mt] = __builtin_amdgcn_mfma_f32_32x32x16_bf16(a2, cv.v, Ot[mt], 0, 0, 0);
      }
    }

    // ---- write prefetched chunk into the other buffer, then barrier
    {
      const int nb = cb ^ 1;
      #pragma unroll
      for (int p = 0; p < 4; ++p)
        *(uint4*)&sm.kv[nb].k[p * 16 + sk_key][sk_d0] = kp[p];
      #pragma unroll
      for (int p = 0; p < 4; ++p)
        *(uint4*)&sm.kv[nb].v[p * 32 + sv_d][sv_k] = vp[p];
    }
    __syncthreads();
  }

  // ---- epilogue (normalized)
  const float inv = 1.0f / lsum;
  const int qrow = q0 + w * 32 + l31;
  float* ob = O + ((size_t)(b * SEQ + qrow)) * HIDDEN + h * HDIM;
  #pragma unroll
  for (int mt = 0; mt < 4; ++mt)
    #pragma unroll
    for (int g = 0; g < 4; ++g) {
      float4 vv = make_float4(Ot[mt][4 * g + 0] * inv, Ot[mt][4 * g + 1] * inv,
                              Ot[mt][4 * g + 2] * inv, Ot[mt][4 * g + 3] * inv);
      *(float4*)&ob[mt * 32 + 8 * g + 4 * hh] = vv;
    }
}

// -------------------------------------------------------------------------- launcher
extern "C" void kernel_launch(void* const* d_in, const int* in_sizes, int n_in,
                              void* d_out, int out_size, void* d_ws, size_t ws_size,
                              hipStream_t stream) {
  (void)in_sizes; (void)n_in; (void)out_size; (void)ws_size;
  const float* X       = (const float*)d_in[0];
  const float* basis_q = (const float*)d_in[1];
  const float* phase_q = (const float*)d_in[2];
  const float* amp_q   = (const float*)d_in[3];
  const float* basis_k = (const float*)d_in[4];
  const float* phase_k = (const float*)d_in[5];
  const float* amp_k   = (const float*)d_in[6];
  const float* basis_v = (const float*)d_in[7];
  const float* phase_v = (const float*)d_in[8];
  const float* amp_v   = (const float*)d_in[9];
  const float* basis_o = (const float*)d_in[10];
  const float* phase_o = (const float*)d_in[11];
  const float* amp_o   = (const float*)d_in[12];

  const size_t WN = (size_t)HIDDEN * HARM;   // 131072

  char* p = (char*)d_ws;
  float* WTq = (float*)p; p += WN * 4;
  float* WTk = (float*)p; p += WN * 4;
  float* WTv = (float*)p; p += WN * 4;
  float* WTo = (float*)p; p += WN * 4;
  float* BTq = (float*)p; p += WN * 4;
  float* BTk = (float*)p; p += WN * 4;
  float* BTv = (float*)p; p += WN * 4;
  float* BTo = (float*)p; p += WN * 4;
  float* Rqp = (float*)p; p += (size_t)4 * RN * 4;
  float* Rkp = (float*)p; p += (size_t)4 * RN * 4;
  float* Rvp = (float*)p; p += (size_t)4 * RN * 4;
  float* Rop = (float*)p; p += (size_t)4 * RN * 4;
  __hip_bfloat16* Qb = (__hip_bfloat16*)p; p += PN * 2;
  __hip_bfloat16* Kb = (__hip_bfloat16*)p; p += PN * 2;
  __hip_bfloat16* Vb = (__hip_bfloat16*)p; p += PN * 2;
  __hip_bfloat16* VtB = (__hip_bfloat16*)p; p += PN * 2;
  float* AO = (float*)p; p += PN * 4;
  float* out = (float*)d_out;

  wt_kernel<<<2048, 256, 0, stream>>>(phase_q, amp_q, phase_k, amp_k,
                                      phase_v, amp_v, phase_o, amp_o,
                                      WTq, WTk, WTv, WTo);
  transpose_basis<<<dim3(64, 2, 4), 256, 0, stream>>>(
      basis_q, basis_k, basis_v, basis_o, BTq, BTk, BTv, BTo);

  resonance_split<<<dim3(64, 4, 3), 256, 0, stream>>>(
      X, BTq, BTk, BTv, Rqp, Rkp, Rvp);

  proj_bf16_f<<<dim3(128, 16, 3), 256, 0, stream>>>(
      Rqp, Rkp, Rvp, WTq, WTk, WTv,
      (ushort*)Qb, (ushort*)Kb, (ushort*)Vb);

  transpose_v<<<dim3(HIDDEN / 32, SEQ / 32, BATCH), 256, 0, stream>>>(
      (const ushort*)Vb, (ushort*)VtB);

  attn_mfma<<<dim3((SEQ / BQ) * 32), 256, 0, stream>>>(
      (const ushort*)Qb, (const ushort*)Kb, (const ushort*)VtB, AO);

  resonance_split<<<dim3(64, 4, 1), 256, 0, stream>>>(
      AO, BTo, BTo, BTo, Rop, Rop, Rop);

  proj_f32<<<dim3(128, 16), 256, 0, stream>>>(Rop, WTo, out);
}

// Round 8
// 310.909 us; speedup vs baseline: 1.3750x; 1.1784x over previous
//
#include <hip/hip_runtime.h>
#include <hip/hip_bf16.h>
#include <math.h>

#define HIDDEN 2048
#define HARM   64
#define NHEADS 16
#define HDIM   128
#define SEQ    2048
#define BATCH  2
#define ROWS   (BATCH*SEQ)   // 4096
#define RN     (ROWS*HARM)   // 262144 (one K-chunk partial plane)
#define PN     ((size_t)ROWS*HIDDEN)  // 8388608

using bf16x8 = __attribute__((ext_vector_type(8))) short;
using f32x16 = __attribute__((ext_vector_type(16))) float;

// hi/lo double-bf16 split: a ~= hi + lo with ~16-bit effective mantissa
__device__ inline void split_bf(float a, ushort& hi, ushort& lo) {
  __hip_bfloat16 h = __float2bfloat16(a);
  float hf = __bfloat162float(h);
  __hip_bfloat16 l = __float2bfloat16(a - hf);
  union { __hip_bfloat16 b; ushort u; } c1, c2;
  c1.b = h; c2.b = l;
  hi = c1.u; lo = c2.u;
}

// ------------------------------------------------ X fp32 -> Xhi, Xlo bf16 (grid 8192)
__global__ __launch_bounds__(256) void cast_x(
    const float* __restrict__ X, ushort* __restrict__ Xh, ushort* __restrict__ Xl) {
  size_t i = ((size_t)blockIdx.x * 256 + threadIdx.x) * 4;
  float4 v = *(const float4*)&X[i];
  ushort4 h, l;
  split_bf(v.x, h.x, l.x); split_bf(v.y, h.y, l.y);
  split_bf(v.z, h.z, l.z); split_bf(v.w, h.w, l.w);
  *(ushort4*)&Xh[i] = h;
  *(ushort4*)&Xl[i] = l;
}

// --------------------- basis q/k/v fp32 [64][2048] -> Bhi/Blo planes (grid 128 x 3)
__global__ __launch_bounds__(256) void cast_basis(
    const float* __restrict__ bq, const float* __restrict__ bk,
    const float* __restrict__ bv,
    ushort* __restrict__ Bh, ushort* __restrict__ Bl) {
  const int z = blockIdx.y;
  const float* S = (z == 0) ? bq : (z == 1) ? bk : bv;
  size_t i = ((size_t)blockIdx.x * 256 + threadIdx.x) * 4;
  float4 v = *(const float4*)&S[i];
  ushort4 h, l;
  split_bf(v.x, h.x, l.x); split_bf(v.y, h.y, l.y);
  split_bf(v.z, h.z, l.z); split_bf(v.w, h.w, l.w);
  size_t o = (size_t)z * HARM * HIDDEN + i;
  *(ushort4*)&Bh[o] = h;
  *(ushort4*)&Bl[o] = l;
}

// ------- w = amp*cos(phase): q/k/v -> Whi/Wlo bf16 in NATIVE [o][h] layout;
//         o-set -> WTo fp32 transposed [h][o] (for the fp32 o-projection)
__global__ __launch_bounds__(256) void wt2_kernel(
    const float* __restrict__ pq, const float* __restrict__ aq,
    const float* __restrict__ pk, const float* __restrict__ ak,
    const float* __restrict__ pv, const float* __restrict__ av,
    const float* __restrict__ po, const float* __restrict__ ao,
    ushort* __restrict__ Wh, ushort* __restrict__ Wl,
    float* __restrict__ To) {
  int i = blockIdx.x * 256 + threadIdx.x;
  const int N = HIDDEN * HARM;
  int set = i / N, j = i - set * N;
  const float* p = (set == 0) ? pq : (set == 1) ? pk : (set == 2) ? pv : po;
  const float* a = (set == 0) ? aq : (set == 1) ? ak : (set == 2) ? av : ao;
  float wv = a[j] * cosf(p[j]);
  if (set < 3) {
    ushort h, l;
    split_bf(wv, h, l);
    size_t o = (size_t)set * N + j;
    Wh[o] = h; Wl[o] = l;
  } else {
    int oo = j >> 6, hhh = j & 63;
    To[(size_t)hhh * HIDDEN + oo] = wv;
  }
}

// --------------------------- basis_o[64][2048] -> BTo[2048][64]  (grid 64 x 2)
__global__ __launch_bounds__(256) void transpose_basis_o(
    const float* __restrict__ S, float* __restrict__ D) {
  const int c0 = blockIdx.x * 32, r0 = blockIdx.y * 32;
  __shared__ float tile[32][33];
  const int t = threadIdx.x;
  const int r = t >> 3, cs = (t & 7) * 4;
  float4 v = *(const float4*)&S[(size_t)(r0 + r) * HIDDEN + c0 + cs];
  tile[r][cs] = v.x; tile[r][cs + 1] = v.y; tile[r][cs + 2] = v.z; tile[r][cs + 3] = v.w;
  __syncthreads();
  float4 o;
  o.x = tile[cs + 0][r]; o.y = tile[cs + 1][r];
  o.z = tile[cs + 2][r]; o.w = tile[cs + 3][r];
  *(float4*)&D[(size_t)(c0 + r) * HARM + r0 + cs] = o;
}

// --------------- MFMA resonance (double-bf16): Rp[kc][M][64] = X * basis^T
// grid (64 Mtiles of 64 rows, 4 K-chunks of 512, 3 bases). A=X rows, B=basis rows
// (native [h][k] layout). 3 MFMA per k-step: hi*hi + lo*hi + hi*lo.
__global__ __launch_bounds__(256) void gemm_res(
    const ushort* __restrict__ Xh, const ushort* __restrict__ Xl,
    const ushort* __restrict__ Bh, const ushort* __restrict__ Bl,
    float* __restrict__ R0, float* __restrict__ R1, float* __restrict__ R2) {
  const int z = blockIdx.z;
  const ushort* Bhz = Bh + (size_t)z * HARM * HIDDEN;
  const ushort* Blz = Bl + (size_t)z * HARM * HIDDEN;
  float* Rp = (z == 0) ? R0 : (z == 1) ? R1 : R2;
  const int row0 = blockIdx.x * 64;
  const int kc = blockIdx.y;
  __shared__ __align__(16) ushort Xs[2][64][72];   // [hi/lo][row][k], stride 72 (36 words)
  __shared__ __align__(16) ushort Bs[2][64][72];   // [hi/lo][h][k]
  const int t = threadIdx.x;
  const int lane = t & 63, w = t >> 6;
  const int l31 = lane & 31, hh = lane >> 5;
  const int m0 = (w & 1) * 32, n0 = (w >> 1) * 32;
  const int srow = t >> 2;            // 0..63
  const int sc = (t & 3) * 16;        // k elem offset
  f32x16 acc;
  #pragma unroll
  for (int j = 0; j < 16; ++j) acc[j] = 0.0f;

  const int kbase = kc * 512;
  for (int k0 = kbase; k0 < kbase + 512; k0 += 64) {
    const size_t xo = (size_t)(row0 + srow) * HIDDEN + k0 + sc;
    const size_t bo = (size_t)srow * HIDDEN + k0 + sc;
    *(uint4*)&Xs[0][srow][sc]     = *(const uint4*)&Xh[xo];
    *(uint4*)&Xs[0][srow][sc + 8] = *(const uint4*)&Xh[xo + 8];
    *(uint4*)&Xs[1][srow][sc]     = *(const uint4*)&Xl[xo];
    *(uint4*)&Xs[1][srow][sc + 8] = *(const uint4*)&Xl[xo + 8];
    *(uint4*)&Bs[0][srow][sc]     = *(const uint4*)&Bhz[bo];
    *(uint4*)&Bs[0][srow][sc + 8] = *(const uint4*)&Bhz[bo + 8];
    *(uint4*)&Bs[1][srow][sc]     = *(const uint4*)&Blz[bo];
    *(uint4*)&Bs[1][srow][sc + 8] = *(const uint4*)&Blz[bo + 8];
    __syncthreads();
    #pragma unroll
    for (int ks = 0; ks < 4; ++ks) {
      bf16x8 ah = *(const bf16x8*)&Xs[0][m0 + l31][ks * 16 + 8 * hh];
      bf16x8 al = *(const bf16x8*)&Xs[1][m0 + l31][ks * 16 + 8 * hh];
      bf16x8 bh = *(const bf16x8*)&Bs[0][n0 + l31][ks * 16 + 8 * hh];
      bf16x8 bl = *(const bf16x8*)&Bs[1][n0 + l31][ks * 16 + 8 * hh];
      acc = __builtin_amdgcn_mfma_f32_32x32x16_bf16(ah, bh, acc, 0, 0, 0);
      acc = __builtin_amdgcn_mfma_f32_32x32x16_bf16(al, bh, acc, 0, 0, 0);
      acc = __builtin_amdgcn_mfma_f32_32x32x16_bf16(ah, bl, acc, 0, 0, 0);
    }
    __syncthreads();
  }
  float* out = Rp + (size_t)kc * ROWS * HARM;
  #pragma unroll
  for (int r = 0; r < 16; ++r) {
    int mloc = (r & 3) + 8 * (r >> 2) + 4 * hh;
    out[(size_t)(row0 + m0 + mloc) * HARM + n0 + l31] = acc[r];
  }
}

// --------------- MFMA projection (double-bf16): P = (sum_kc Rp) * W^T, bf16 out
// grid (128 Mtiles of 32 rows, 16 Ntiles of 128 cols, 3). W native [o][h].
__global__ __launch_bounds__(256) void gemm_proj(
    const float* __restrict__ Rp0, const float* __restrict__ Rp1,
    const float* __restrict__ Rp2,
    const ushort* __restrict__ Wh, const ushort* __restrict__ Wl,
    ushort* __restrict__ P0, ushort* __restrict__ P1, ushort* __restrict__ P2) {
  const int z = blockIdx.z;
  const float* Rp = (z == 0) ? Rp0 : (z == 1) ? Rp1 : Rp2;
  const ushort* Whz = Wh + (size_t)z * HIDDEN * HARM;
  const ushort* Wlz = Wl + (size_t)z * HIDDEN * HARM;
  ushort* P = (z == 0) ? P0 : (z == 1) ? P1 : P2;
  const int row0 = blockIdx.x * 32;
  const int col0 = blockIdx.y * 128;
  __shared__ __align__(16) ushort Rs[2][32][72];
  __shared__ __align__(16) ushort Ws[2][128][72];
  const int t = threadIdx.x;
  const int lane = t & 63, w = t >> 6;
  const int l31 = lane & 31, hh = lane >> 5;
  // ---- stage R: reduce 4 split-K planes fp32, then hi/lo split into LDS
  {
    const int r = t >> 3, h0 = (t & 7) * 8;
    const size_t o = (size_t)(row0 + r) * HARM + h0;
    #pragma unroll
    for (int e = 0; e < 8; ++e) {
      float v = Rp[o + e] + Rp[RN + o + e] + Rp[2 * (size_t)RN + o + e] +
                Rp[3 * (size_t)RN + o + e];
      ushort hi, lo;
      split_bf(v, hi, lo);
      Rs[0][r][h0 + e] = hi;
      Rs[1][r][h0 + e] = lo;
    }
  }
  // ---- stage W: 128 rows x 64 k, hi+lo
  #pragma unroll
  for (int i = 0; i < 4; ++i) {
    int idx = t + i * 256;
    int o = idx >> 3, c8 = (idx & 7) * 8;
    const size_t go = (size_t)(col0 + o) * HARM + c8;
    *(uint4*)&Ws[0][o][c8] = *(const uint4*)&Whz[go];
    *(uint4*)&Ws[1][o][c8] = *(const uint4*)&Wlz[go];
  }
  __syncthreads();
  const int n0 = w * 32;
  f32x16 acc;
  #pragma unroll
  for (int j = 0; j < 16; ++j) acc[j] = 0.0f;
  #pragma unroll
  for (int ks = 0; ks < 4; ++ks) {
    bf16x8 ah = *(const bf16x8*)&Rs[0][l31][ks * 16 + 8 * hh];
    bf16x8 al = *(const bf16x8*)&Rs[1][l31][ks * 16 + 8 * hh];
    bf16x8 bh = *(const bf16x8*)&Ws[0][n0 + l31][ks * 16 + 8 * hh];
    bf16x8 bl = *(const bf16x8*)&Ws[1][n0 + l31][ks * 16 + 8 * hh];
    acc = __builtin_amdgcn_mfma_f32_32x32x16_bf16(ah, bh, acc, 0, 0, 0);
    acc = __builtin_amdgcn_mfma_f32_32x32x16_bf16(al, bh, acc, 0, 0, 0);
    acc = __builtin_amdgcn_mfma_f32_32x32x16_bf16(ah, bl, acc, 0, 0, 0);
  }
  #pragma unroll
  for (int r = 0; r < 16; ++r) {
    int mloc = (r & 3) + 8 * (r >> 2) + 4 * hh;
    union { __hip_bfloat16 b; ushort u; } cv;
    cv.b = __float2bfloat16(acc[r]);
    P[(size_t)(row0 + mloc) * HIDDEN + col0 + n0 + l31] = cv.u;
  }
}

// --------------- fp32 split-K resonance for the O-path (unchanged from R4/R7)
__global__ __launch_bounds__(256) void resonance_split(
    const float* __restrict__ X,
    const float* __restrict__ B0, const float* __restrict__ B1,
    const float* __restrict__ B2,
    float* __restrict__ R0, float* __restrict__ R1, float* __restrict__ R2) {
  const int z = blockIdx.z;
  const float* BT = (z == 0) ? B0 : (z == 1) ? B1 : B2;
  float* Rp = (z == 0) ? R0 : (z == 1) ? R1 : R2;
  const int row0 = blockIdx.x * 64;
  const int kc = blockIdx.y;
  __shared__ float Xt[32][68];
  __shared__ float Bt[32][68];
  const int tid = threadIdx.x;
  const int ty = tid >> 4, tx = tid & 15;
  float acc[4][4] = {};
  const int kbase = kc * 512;
  for (int k0 = kbase; k0 < kbase + 512; k0 += 32) {
    #pragma unroll
    for (int i = 0; i < 8; ++i) {
      int idx = tid + i * 256;
      int r = idx >> 5, kk = idx & 31;
      Xt[kk][r] = X[(size_t)(row0 + r) * HIDDEN + k0 + kk];
      int rb = idx & 63, kb = idx >> 6;
      Bt[kb][rb] = BT[(size_t)(k0 + kb) * HARM + rb];
    }
    __syncthreads();
    #pragma unroll
    for (int kk = 0; kk < 32; ++kk) {
      float4 xv = *(const float4*)&Xt[kk][ty * 4];
      float4 bv = *(const float4*)&Bt[kk][tx * 4];
      acc[0][0] += xv.x * bv.x; acc[0][1] += xv.x * bv.y; acc[0][2] += xv.x * bv.z; acc[0][3] += xv.x * bv.w;
      acc[1][0] += xv.y * bv.x; acc[1][1] += xv.y * bv.y; acc[1][2] += xv.y * bv.z; acc[1][3] += xv.y * bv.w;
      acc[2][0] += xv.z * bv.x; acc[2][1] += xv.z * bv.y; acc[2][2] += xv.z * bv.z; acc[2][3] += xv.z * bv.w;
      acc[3][0] += xv.w * bv.x; acc[3][1] += xv.w * bv.y; acc[3][2] += xv.w * bv.z; acc[3][3] += xv.w * bv.w;
    }
    __syncthreads();
  }
  #pragma unroll
  for (int i = 0; i < 4; ++i) {
    float4 v = make_float4(acc[i][0], acc[i][1], acc[i][2], acc[i][3]);
    *(float4*)&Rp[(size_t)(kc * ROWS + row0 + ty * 4 + i) * HARM + tx * 4] = v;
  }
}

// fp32-output o-projection (unchanged), grid (128, 16)
__global__ __launch_bounds__(256) void proj_f32(
    const float* __restrict__ Rp, const float* __restrict__ WT,
    float* __restrict__ P) {
  const int row0 = blockIdx.x * 32;
  const int col0 = blockIdx.y * 128;
  __shared__ float Rt[64][36];
  __shared__ float Wt[64][132];
  const int tid = threadIdx.x;
  #pragma unroll
  for (int i = 0; i < 8; ++i) {
    int idx = tid + i * 256;
    int r = idx >> 6, kk = idx & 63;
    size_t o = (size_t)(row0 + r) * HARM + kk;
    Rt[kk][r] = Rp[o] + Rp[RN + o] + Rp[2 * (size_t)RN + o] + Rp[3 * (size_t)RN + o];
  }
  #pragma unroll
  for (int i = 0; i < 32; ++i) {
    int idx = tid + i * 256;
    int c = idx & 127, kk = idx >> 7;
    Wt[kk][c] = WT[(size_t)kk * HIDDEN + col0 + c];
  }
  __syncthreads();
  const int ty = tid >> 5, tx = tid & 31;
  float acc[4][4] = {};
  #pragma unroll
  for (int kk = 0; kk < 64; ++kk) {
    float4 rv = *(const float4*)&Rt[kk][ty * 4];
    float4 wv = *(const float4*)&Wt[kk][tx * 4];
    acc[0][0] += rv.x * wv.x; acc[0][1] += rv.x * wv.y; acc[0][2] += rv.x * wv.z; acc[0][3] += rv.x * wv.w;
    acc[1][0] += rv.y * wv.x; acc[1][1] += rv.y * wv.y; acc[1][2] += rv.y * wv.z; acc[1][3] += rv.y * wv.w;
    acc[2][0] += rv.z * wv.x; acc[2][1] += rv.z * wv.y; acc[2][2] += rv.z * wv.z; acc[2][3] += rv.z * wv.w;
    acc[3][0] += rv.w * wv.x; acc[3][1] += rv.w * wv.y; acc[3][2] += rv.w * wv.z; acc[3][3] += rv.w * wv.w;
  }
  #pragma unroll
  for (int i = 0; i < 4; ++i) {
    float4 v = make_float4(acc[i][0], acc[i][1], acc[i][2], acc[i][3]);
    *(float4*)&P[(size_t)(row0 + ty * 4 + i) * HIDDEN + col0 + tx * 4] = v;
  }
}

// -------------------------------------- per-batch 2048x2048 bf16 transpose (V -> V^T)
__global__ __launch_bounds__(256) void transpose_v(
    const ushort* __restrict__ S, ushort* __restrict__ D) {
  const int b = blockIdx.z;
  const int r0 = blockIdx.y * 32, c0 = blockIdx.x * 32;
  __shared__ ushort tile[32][33];
  const int t = threadIdx.x;
  const int r = t >> 3, cs = (t & 7) * 4;
  const ushort* Sb = S + (size_t)b * SEQ * HIDDEN;
  ushort* Db = D + (size_t)b * SEQ * HIDDEN;
  ushort4 v = *(const ushort4*)&Sb[(size_t)(r0 + r) * HIDDEN + c0 + cs];
  tile[r][cs] = v.x; tile[r][cs + 1] = v.y; tile[r][cs + 2] = v.z; tile[r][cs + 3] = v.w;
  __syncthreads();
  ushort4 o;
  o.x = tile[cs + 0][r]; o.y = tile[cs + 1][r];
  o.z = tile[cs + 2][r]; o.w = tile[cs + 3][r];
  *(ushort4*)&Db[(size_t)(c0 + r) * SEQ + r0 + cs] = o;
}

// ----------------------------------------------------------- MFMA flash attention
// R7 version (double-buffered KV prefetch) — UNCHANGED (control).
#define BQ 128
#define BK 64
#define KSTR 136
#define VSTR 72

__device__ inline unsigned pkbf(float a, float b) {
  __hip_bfloat162 h2 = __float22bfloat162_rn(make_float2(a, b));
  union { __hip_bfloat162 h; unsigned u; } cv; cv.h = h2; return cv.u;
}

__global__ __launch_bounds__(256, 2) void attn_mfma(
    const ushort* __restrict__ Qg, const ushort* __restrict__ Kg,
    const ushort* __restrict__ Vt, float* __restrict__ O) {
  __shared__ __align__(16) union SM {
    ushort q[BQ][KSTR];
    struct { ushort k[BK][KSTR]; ushort v[HDIM][VSTR]; } kv[2];
  } sm;
  const int t = threadIdx.x;
  const int bh = blockIdx.x & 31;
  const int qt = blockIdx.x >> 5;
  const int b = bh >> 4, h = bh & 15;
  const int q0 = qt * BQ;
  const int lane = t & 63;
  const int w = t >> 6;
  const int l31 = lane & 31;
  const int hh = lane >> 5;
  const bool hi = (hh != 0);
  const float SC2 = 0.08838834764831845f * 1.4426950408889634f;

  const int sk_key = t >> 4;
  const int sk_d0 = (t & 15) * 8;
  const int sv_d = t >> 3;
  const int sv_k = (t & 7) * 8;
  const size_t kbase = ((size_t)(b * SEQ)) * HIDDEN + h * HDIM;
  const size_t vbase = ((size_t)(b * SEQ + h * HDIM)) * SEQ;

  {
    const size_t gbase = ((size_t)(b * SEQ + q0)) * HIDDEN + h * HDIM;
    for (int p = 0; p < 8; ++p) {
      int row = p * 16 + sk_key;
      uint4 v = *(const uint4*)&Qg[gbase + (size_t)row * HIDDEN + sk_d0];
      *(uint4*)&sm.q[row][sk_d0] = v;
    }
  }
  __syncthreads();
  bf16x8 Qf[8];
  {
    const int qrow = w * 32 + l31;
    #pragma unroll
    for (int ks = 0; ks < 8; ++ks)
      Qf[ks] = *(const bf16x8*)&sm.q[qrow][ks * 16 + 8 * hh];
  }
  __syncthreads();

  float mrow = -1e30f, lsum = 0.0f;
  f32x16 Ot[4];
  #pragma unroll
  for (int i = 0; i < 4; ++i)
    #pragma unroll
    for (int j = 0; j < 16; ++j) Ot[i][j] = 0.0f;

  uint4 kp[4], vp[4];
  {
    const size_t gb = kbase;
    #pragma unroll
    for (int p = 0; p < 4; ++p)
      kp[p] = *(const uint4*)&Kg[gb + (size_t)(p * 16 + sk_key) * HIDDEN + sk_d0];
    #pragma unroll
    for (int p = 0; p < 4; ++p)
      vp[p] = *(const uint4*)&Vt[vbase + (size_t)(p * 32 + sv_d) * SEQ + sv_k];
    #pragma unroll
    for (int p = 0; p < 4; ++p)
      *(uint4*)&sm.kv[0].k[p * 16 + sk_key][sk_d0] = kp[p];
    #pragma unroll
    for (int p = 0; p < 4; ++p)
      *(uint4*)&sm.kv[0].v[p * 32 + sv_d][sv_k] = vp[p];
  }
  __syncthreads();

  for (int ci = 0; ci < 32; ++ci) {
    {
      const int cn = (ci < 31) ? ci + 1 : 31;
      const size_t gb = kbase + (size_t)(cn * BK) * HIDDEN;
      #pragma unroll
      for (int p = 0; p < 4; ++p)
        kp[p] = *(const uint4*)&Kg[gb + (size_t)(p * 16 + sk_key) * HIDDEN + sk_d0];
      const size_t vb = vbase + cn * BK;
      #pragma unroll
      for (int p = 0; p < 4; ++p)
        vp[p] = *(const uint4*)&Vt[vb + (size_t)(p * 32 + sv_d) * SEQ + sv_k];
    }
    const int cb = ci & 1;

    f32x16 C0, C1;
    #pragma unroll
    for (int j = 0; j < 16; ++j) { C0[j] = 0.0f; C1[j] = 0.0f; }
    #pragma unroll
    for (int ks = 0; ks < 8; ++ks) {
      bf16x8 a0 = *(const bf16x8*)&sm.kv[cb].k[l31][ks * 16 + 8 * hh];
      bf16x8 a1 = *(const bf16x8*)&sm.kv[cb].k[32 + l31][ks * 16 + 8 * hh];
      C0 = __builtin_amdgcn_mfma_f32_32x32x16_bf16(a0, Qf[ks], C0, 0, 0, 0);
      C1 = __builtin_amdgcn_mfma_f32_32x32x16_bf16(a1, Qf[ks], C1, 0, 0, 0);
    }

    float mxr = -1e30f;
    #pragma unroll
    for (int j = 0; j < 16; ++j) mxr = fmaxf(mxr, fmaxf(C0[j], C1[j]));
    mxr = fmaxf(mxr, __shfl_xor(mxr, 32));
    const float mnew = fmaxf(mrow, mxr * SC2);
    const float alpha = exp2f(mrow - mnew);
    float ssum = 0.0f;
    #pragma unroll
    for (int j = 0; j < 16; ++j) {
      float e0 = exp2f(fmaf(C0[j], SC2, -mnew));
      float e1 = exp2f(fmaf(C1[j], SC2, -mnew));
      C0[j] = e0; C1[j] = e1;
      ssum += e0 + e1;
    }
    ssum += __shfl_xor(ssum, 32);
    lsum = lsum * alpha + ssum;
    mrow = mnew;
    #pragma unroll
    for (int i = 0; i < 4; ++i)
      #pragma unroll
      for (int j = 0; j < 16; ++j) Ot[i][j] *= alpha;

    #pragma unroll
    for (int st = 0; st < 4; ++st) {
      const int eb = 8 * (st & 1);
      float o0, o1, o2, o3, g0, g1, g2, g3;
      if (st < 2) {
        o0 = hi ? C0[eb + 4] : C0[eb + 0]; o1 = hi ? C0[eb + 5] : C0[eb + 1];
        o2 = hi ? C0[eb + 6] : C0[eb + 2]; o3 = hi ? C0[eb + 7] : C0[eb + 3];
        g0 = hi ? C0[eb + 0] : C0[eb + 4]; g1 = hi ? C0[eb + 1] : C0[eb + 5];
        g2 = hi ? C0[eb + 2] : C0[eb + 6]; g3 = hi ? C0[eb + 3] : C0[eb + 7];
      } else {
        o0 = hi ? C1[eb + 4] : C1[eb + 0]; o1 = hi ? C1[eb + 5] : C1[eb + 1];
        o2 = hi ? C1[eb + 6] : C1[eb + 2]; o3 = hi ? C1[eb + 7] : C1[eb + 3];
        g0 = hi ? C1[eb + 0] : C1[eb + 4]; g1 = hi ? C1[eb + 1] : C1[eb + 5];
        g2 = hi ? C1[eb + 2] : C1[eb + 6]; g3 = hi ? C1[eb + 3] : C1[eb + 7];
      }
      unsigned so0 = pkbf(o0, o1), so1 = pkbf(o2, o3);
      unsigned sp0 = pkbf(g0, g1), sp1 = pkbf(g2, g3);
      unsigned r0 = (unsigned)__shfl_xor((int)sp0, 32);
      unsigned r1 = (unsigned)__shfl_xor((int)sp1, 32);
      union { unsigned u[4]; bf16x8 v; } cv;
      cv.u[0] = hi ? r0 : so0;
      cv.u[1] = hi ? r1 : so1;
      cv.u[2] = hi ? so0 : r0;
      cv.u[3] = hi ? so1 : r1;
      #pragma unroll
      for (int mt = 0; mt < 4; ++mt) {
        bf16x8 a2 = *(const bf16x8*)&sm.kv[cb].v[mt * 32 + l31][st * 16 + 8 * hh];
        Ot[mt] = __builtin_amdgcn_mfma_f32_32x32x16_bf16(a2, cv.v, Ot[mt], 0, 0, 0);
      }
    }

    {
      const int nb = cb ^ 1;
      #pragma unroll
      for (int p = 0; p < 4; ++p)
        *(uint4*)&sm.kv[nb].k[p * 16 + sk_key][sk_d0] = kp[p];
      #pragma unroll
      for (int p = 0; p < 4; ++p)
        *(uint4*)&sm.kv[nb].v[p * 32 + sv_d][sv_k] = vp[p];
    }
    __syncthreads();
  }

  const float inv = 1.0f / lsum;
  const int qrow = q0 + w * 32 + l31;
  float* ob = O + ((size_t)(b * SEQ + qrow)) * HIDDEN + h * HDIM;
  #pragma unroll
  for (int mt = 0; mt < 4; ++mt)
    #pragma unroll
    for (int g = 0; g < 4; ++g) {
      float4 vv = make_float4(Ot[mt][4 * g + 0] * inv, Ot[mt][4 * g + 1] * inv,
                              Ot[mt][4 * g + 2] * inv, Ot[mt][4 * g + 3] * inv);
      *(float4*)&ob[mt * 32 + 8 * g + 4 * hh] = vv;
    }
}

// -------------------------------------------------------------------------- launcher
extern "C" void kernel_launch(void* const* d_in, const int* in_sizes, int n_in,
                              void* d_out, int out_size, void* d_ws, size_t ws_size,
                              hipStream_t stream) {
  (void)in_sizes; (void)n_in; (void)out_size; (void)ws_size;
  const float* X       = (const float*)d_in[0];
  const float* basis_q = (const float*)d_in[1];
  const float* phase_q = (const float*)d_in[2];
  const float* amp_q   = (const float*)d_in[3];
  const float* basis_k = (const float*)d_in[4];
  const float* phase_k = (const float*)d_in[5];
  const float* amp_k   = (const float*)d_in[6];
  const float* basis_v = (const float*)d_in[7];
  const float* phase_v = (const float*)d_in[8];
  const float* amp_v   = (const float*)d_in[9];
  const float* basis_o = (const float*)d_in[10];
  const float* phase_o = (const float*)d_in[11];
  const float* amp_o   = (const float*)d_in[12];

  const size_t WN = (size_t)HIDDEN * HARM;   // 131072

  char* p = (char*)d_ws;
  ushort* Xhi = (ushort*)p; p += PN * 2;
  ushort* Xlo = (ushort*)p; p += PN * 2;
  ushort* Bhi = (ushort*)p; p += 3 * WN * 2;
  ushort* Blo = (ushort*)p; p += 3 * WN * 2;
  ushort* Whi = (ushort*)p; p += 3 * WN * 2;
  ushort* Wlo = (ushort*)p; p += 3 * WN * 2;
  float* WTo = (float*)p; p += WN * 4;
  float* BTo = (float*)p; p += WN * 4;
  float* Rqp = (float*)p; p += (size_t)4 * RN * 4;
  float* Rkp = (float*)p; p += (size_t)4 * RN * 4;
  float* Rvp = (float*)p; p += (size_t)4 * RN * 4;
  float* Rop = (float*)p; p += (size_t)4 * RN * 4;
  __hip_bfloat16* Qb = (__hip_bfloat16*)p; p += PN * 2;
  __hip_bfloat16* Kb = (__hip_bfloat16*)p; p += PN * 2;
  __hip_bfloat16* Vb = (__hip_bfloat16*)p; p += PN * 2;
  __hip_bfloat16* VtB = (__hip_bfloat16*)p; p += PN * 2;
  float* AO = (float*)p; p += PN * 4;
  float* out = (float*)d_out;

  cast_x<<<8192, 256, 0, stream>>>(X, Xhi, Xlo);
  wt2_kernel<<<2048, 256, 0, stream>>>(phase_q, amp_q, phase_k, amp_k,
                                       phase_v, amp_v, phase_o, amp_o,
                                       Whi, Wlo, WTo);
  cast_basis<<<dim3(128, 3), 256, 0, stream>>>(basis_q, basis_k, basis_v, Bhi, Blo);
  transpose_basis_o<<<dim3(64, 2), 256, 0, stream>>>(basis_o, BTo);

  gemm_res<<<dim3(64, 4, 3), 256, 0, stream>>>(Xhi, Xlo, Bhi, Blo, Rqp, Rkp, Rvp);

  gemm_proj<<<dim3(128, 16, 3), 256, 0, stream>>>(
      Rqp, Rkp, Rvp, Whi, Wlo, (ushort*)Qb, (ushort*)Kb, (ushort*)Vb);

  transpose_v<<<dim3(HIDDEN / 32, SEQ / 32, BATCH), 256, 0, stream>>>(
      (const ushort*)Vb, (ushort*)VtB);

  attn_mfma<<<dim3((SEQ / BQ) * 32), 256, 0, stream>>>(
      (const ushort*)Qb, (const ushort*)Kb, (const ushort*)VtB, AO);

  resonance_split<<<dim3(64, 4, 1), 256, 0, stream>>>(
      AO, BTo, BTo, BTo, Rop, Rop, Rop);

  proj_f32<<<dim3(128, 16), 256, 0, stream>>>(Rop, WTo, out);
}

// Round 9
// 286.641 us; speedup vs baseline: 1.4915x; 1.0847x over previous
//
#include <hip/hip_runtime.h>
#include <hip/hip_bf16.h>
#include <math.h>

#define HIDDEN 2048
#define HARM   64
#define NHEADS 16
#define HDIM   128
#define SEQ    2048
#define BATCH  2
#define ROWS   (BATCH*SEQ)   // 4096
#define RN     (ROWS*HARM)   // 262144 (one K-chunk partial plane)
#define PN     ((size_t)ROWS*HIDDEN)  // 8388608

using bf16x8 = __attribute__((ext_vector_type(8))) short;
using f32x16 = __attribute__((ext_vector_type(16))) float;

// hi/lo double-bf16 split: a ~= hi + lo with ~16-bit effective mantissa
__device__ inline void split_bf(float a, ushort& hi, ushort& lo) {
  __hip_bfloat16 h = __float2bfloat16(a);
  float hf = __bfloat162float(h);
  __hip_bfloat16 l = __float2bfloat16(a - hf);
  union { __hip_bfloat16 b; ushort u; } c1, c2;
  c1.b = h; c2.b = l;
  hi = c1.u; lo = c2.u;
}

// ------------------------------------------------ X fp32 -> Xhi, Xlo bf16 (grid 8192)
__global__ __launch_bounds__(256) void cast_x(
    const float* __restrict__ X, ushort* __restrict__ Xh, ushort* __restrict__ Xl) {
  size_t i = ((size_t)blockIdx.x * 256 + threadIdx.x) * 4;
  float4 v = *(const float4*)&X[i];
  ushort4 h, l;
  split_bf(v.x, h.x, l.x); split_bf(v.y, h.y, l.y);
  split_bf(v.z, h.z, l.z); split_bf(v.w, h.w, l.w);
  *(ushort4*)&Xh[i] = h;
  *(ushort4*)&Xl[i] = l;
}

// --------------------- basis q/k/v/o fp32 [64][2048] -> Bhi/Blo planes (grid 128 x 4)
__global__ __launch_bounds__(256) void cast_basis(
    const float* __restrict__ bq, const float* __restrict__ bk,
    const float* __restrict__ bv, const float* __restrict__ bo,
    ushort* __restrict__ Bh, ushort* __restrict__ Bl) {
  const int z = blockIdx.y;
  const float* S = (z == 0) ? bq : (z == 1) ? bk : (z == 2) ? bv : bo;
  size_t i = ((size_t)blockIdx.x * 256 + threadIdx.x) * 4;
  float4 v = *(const float4*)&S[i];
  ushort4 h, l;
  split_bf(v.x, h.x, l.x); split_bf(v.y, h.y, l.y);
  split_bf(v.z, h.z, l.z); split_bf(v.w, h.w, l.w);
  size_t o = (size_t)z * HARM * HIDDEN + i;
  *(ushort4*)&Bh[o] = h;
  *(ushort4*)&Bl[o] = l;
}

// ------- w = amp*cos(phase) for all 4 sets -> Whi/Wlo bf16, NATIVE [o][h] layout
__global__ __launch_bounds__(256) void wt2_kernel(
    const float* __restrict__ pq, const float* __restrict__ aq,
    const float* __restrict__ pk, const float* __restrict__ ak,
    const float* __restrict__ pv, const float* __restrict__ av,
    const float* __restrict__ po, const float* __restrict__ ao,
    ushort* __restrict__ Wh, ushort* __restrict__ Wl) {
  int i = blockIdx.x * 256 + threadIdx.x;
  const int N = HIDDEN * HARM;
  int set = i / N, j = i - set * N;
  const float* p = (set == 0) ? pq : (set == 1) ? pk : (set == 2) ? pv : po;
  const float* a = (set == 0) ? aq : (set == 1) ? ak : (set == 2) ? av : ao;
  float wv = a[j] * cosf(p[j]);
  ushort h, l;
  split_bf(wv, h, l);
  size_t o = (size_t)set * N + j;
  Wh[o] = h; Wl[o] = l;
}

// --------------- MFMA resonance (double-bf16): Rp[kc][M][64] = X * basis^T
// grid (64 Mtiles of 64 rows, 4 K-chunks of 512, nb bases). A=X rows, B=basis rows
// (native [h][k] layout). 3 MFMA per k-step: hi*hi + lo*hi + hi*lo.
__global__ __launch_bounds__(256) void gemm_res(
    const ushort* __restrict__ Xh, const ushort* __restrict__ Xl,
    const ushort* __restrict__ Bh, const ushort* __restrict__ Bl,
    float* __restrict__ R0, float* __restrict__ R1, float* __restrict__ R2) {
  const int z = blockIdx.z;
  const ushort* Bhz = Bh + (size_t)z * HARM * HIDDEN;
  const ushort* Blz = Bl + (size_t)z * HARM * HIDDEN;
  float* Rp = (z == 0) ? R0 : (z == 1) ? R1 : R2;
  const int row0 = blockIdx.x * 64;
  const int kc = blockIdx.y;
  __shared__ __align__(16) ushort Xs[2][64][72];   // [hi/lo][row][k]
  __shared__ __align__(16) ushort Bs[2][64][72];   // [hi/lo][h][k]
  const int t = threadIdx.x;
  const int lane = t & 63, w = t >> 6;
  const int l31 = lane & 31, hh = lane >> 5;
  const int m0 = (w & 1) * 32, n0 = (w >> 1) * 32;
  const int srow = t >> 2;            // 0..63
  const int sc = (t & 3) * 16;        // k elem offset
  f32x16 acc;
  #pragma unroll
  for (int j = 0; j < 16; ++j) acc[j] = 0.0f;

  const int kbase = kc * 512;
  for (int k0 = kbase; k0 < kbase + 512; k0 += 64) {
    const size_t xo = (size_t)(row0 + srow) * HIDDEN + k0 + sc;
    const size_t bo = (size_t)srow * HIDDEN + k0 + sc;
    *(uint4*)&Xs[0][srow][sc]     = *(const uint4*)&Xh[xo];
    *(uint4*)&Xs[0][srow][sc + 8] = *(const uint4*)&Xh[xo + 8];
    *(uint4*)&Xs[1][srow][sc]     = *(const uint4*)&Xl[xo];
    *(uint4*)&Xs[1][srow][sc + 8] = *(const uint4*)&Xl[xo + 8];
    *(uint4*)&Bs[0][srow][sc]     = *(const uint4*)&Bhz[bo];
    *(uint4*)&Bs[0][srow][sc + 8] = *(const uint4*)&Bhz[bo + 8];
    *(uint4*)&Bs[1][srow][sc]     = *(const uint4*)&Blz[bo];
    *(uint4*)&Bs[1][srow][sc + 8] = *(const uint4*)&Blz[bo + 8];
    __syncthreads();
    #pragma unroll
    for (int ks = 0; ks < 4; ++ks) {
      bf16x8 ah = *(const bf16x8*)&Xs[0][m0 + l31][ks * 16 + 8 * hh];
      bf16x8 al = *(const bf16x8*)&Xs[1][m0 + l31][ks * 16 + 8 * hh];
      bf16x8 bh = *(const bf16x8*)&Bs[0][n0 + l31][ks * 16 + 8 * hh];
      bf16x8 bl = *(const bf16x8*)&Bs[1][n0 + l31][ks * 16 + 8 * hh];
      acc = __builtin_amdgcn_mfma_f32_32x32x16_bf16(ah, bh, acc, 0, 0, 0);
      acc = __builtin_amdgcn_mfma_f32_32x32x16_bf16(al, bh, acc, 0, 0, 0);
      acc = __builtin_amdgcn_mfma_f32_32x32x16_bf16(ah, bl, acc, 0, 0, 0);
    }
    __syncthreads();
  }
  float* out = Rp + (size_t)kc * ROWS * HARM;
  #pragma unroll
  for (int r = 0; r < 16; ++r) {
    int mloc = (r & 3) + 8 * (r >> 2) + 4 * hh;
    out[(size_t)(row0 + m0 + mloc) * HARM + n0 + l31] = acc[r];
  }
}

// --------------- MFMA projection (double-bf16): P = (sum_kc Rp) * W^T, bf16 out
// grid (128 Mtiles of 32 rows, 16 Ntiles of 128 cols, 3). W native [o][h].
__global__ __launch_bounds__(256) void gemm_proj(
    const float* __restrict__ Rp0, const float* __restrict__ Rp1,
    const float* __restrict__ Rp2,
    const ushort* __restrict__ Wh, const ushort* __restrict__ Wl,
    ushort* __restrict__ P0, ushort* __restrict__ P1, ushort* __restrict__ P2) {
  const int z = blockIdx.z;
  const float* Rp = (z == 0) ? Rp0 : (z == 1) ? Rp1 : Rp2;
  const ushort* Whz = Wh + (size_t)z * HIDDEN * HARM;
  const ushort* Wlz = Wl + (size_t)z * HIDDEN * HARM;
  ushort* P = (z == 0) ? P0 : (z == 1) ? P1 : P2;
  const int row0 = blockIdx.x * 32;
  const int col0 = blockIdx.y * 128;
  __shared__ __align__(16) ushort Rs[2][32][72];
  __shared__ __align__(16) ushort Ws[2][128][72];
  const int t = threadIdx.x;
  const int lane = t & 63, w = t >> 6;
  const int l31 = lane & 31, hh = lane >> 5;
  {
    const int r = t >> 3, h0 = (t & 7) * 8;
    const size_t o = (size_t)(row0 + r) * HARM + h0;
    #pragma unroll
    for (int e = 0; e < 8; ++e) {
      float v = Rp[o + e] + Rp[RN + o + e] + Rp[2 * (size_t)RN + o + e] +
                Rp[3 * (size_t)RN + o + e];
      ushort hi, lo;
      split_bf(v, hi, lo);
      Rs[0][r][h0 + e] = hi;
      Rs[1][r][h0 + e] = lo;
    }
  }
  #pragma unroll
  for (int i = 0; i < 4; ++i) {
    int idx = t + i * 256;
    int o = idx >> 3, c8 = (idx & 7) * 8;
    const size_t go = (size_t)(col0 + o) * HARM + c8;
    *(uint4*)&Ws[0][o][c8] = *(const uint4*)&Whz[go];
    *(uint4*)&Ws[1][o][c8] = *(const uint4*)&Wlz[go];
  }
  __syncthreads();
  const int n0 = w * 32;
  f32x16 acc;
  #pragma unroll
  for (int j = 0; j < 16; ++j) acc[j] = 0.0f;
  #pragma unroll
  for (int ks = 0; ks < 4; ++ks) {
    bf16x8 ah = *(const bf16x8*)&Rs[0][l31][ks * 16 + 8 * hh];
    bf16x8 al = *(const bf16x8*)&Rs[1][l31][ks * 16 + 8 * hh];
    bf16x8 bh = *(const bf16x8*)&Ws[0][n0 + l31][ks * 16 + 8 * hh];
    bf16x8 bl = *(const bf16x8*)&Ws[1][n0 + l31][ks * 16 + 8 * hh];
    acc = __builtin_amdgcn_mfma_f32_32x32x16_bf16(ah, bh, acc, 0, 0, 0);
    acc = __builtin_amdgcn_mfma_f32_32x32x16_bf16(al, bh, acc, 0, 0, 0);
    acc = __builtin_amdgcn_mfma_f32_32x32x16_bf16(ah, bl, acc, 0, 0, 0);
  }
  #pragma unroll
  for (int r = 0; r < 16; ++r) {
    int mloc = (r & 3) + 8 * (r >> 2) + 4 * hh;
    union { __hip_bfloat16 b; ushort u; } cv;
    cv.b = __float2bfloat16(acc[r]);
    P[(size_t)(row0 + mloc) * HIDDEN + col0 + n0 + l31] = cv.u;
  }
}

// --------------- MFMA final projection (double-bf16, fp32 out), grid (128, 16)
__global__ __launch_bounds__(256) void gemm_proj_f32(
    const float* __restrict__ Rp,
    const ushort* __restrict__ Whz, const ushort* __restrict__ Wlz,
    float* __restrict__ P) {
  const int row0 = blockIdx.x * 32;
  const int col0 = blockIdx.y * 128;
  __shared__ __align__(16) ushort Rs[2][32][72];
  __shared__ __align__(16) ushort Ws[2][128][72];
  const int t = threadIdx.x;
  const int lane = t & 63, w = t >> 6;
  const int l31 = lane & 31, hh = lane >> 5;
  {
    const int r = t >> 3, h0 = (t & 7) * 8;
    const size_t o = (size_t)(row0 + r) * HARM + h0;
    #pragma unroll
    for (int e = 0; e < 8; ++e) {
      float v = Rp[o + e] + Rp[RN + o + e] + Rp[2 * (size_t)RN + o + e] +
                Rp[3 * (size_t)RN + o + e];
      ushort hi, lo;
      split_bf(v, hi, lo);
      Rs[0][r][h0 + e] = hi;
      Rs[1][r][h0 + e] = lo;
    }
  }
  #pragma unroll
  for (int i = 0; i < 4; ++i) {
    int idx = t + i * 256;
    int o = idx >> 3, c8 = (idx & 7) * 8;
    const size_t go = (size_t)(col0 + o) * HARM + c8;
    *(uint4*)&Ws[0][o][c8] = *(const uint4*)&Whz[go];
    *(uint4*)&Ws[1][o][c8] = *(const uint4*)&Wlz[go];
  }
  __syncthreads();
  const int n0 = w * 32;
  f32x16 acc;
  #pragma unroll
  for (int j = 0; j < 16; ++j) acc[j] = 0.0f;
  #pragma unroll
  for (int ks = 0; ks < 4; ++ks) {
    bf16x8 ah = *(const bf16x8*)&Rs[0][l31][ks * 16 + 8 * hh];
    bf16x8 al = *(const bf16x8*)&Rs[1][l31][ks * 16 + 8 * hh];
    bf16x8 bh = *(const bf16x8*)&Ws[0][n0 + l31][ks * 16 + 8 * hh];
    bf16x8 bl = *(const bf16x8*)&Ws[1][n0 + l31][ks * 16 + 8 * hh];
    acc = __builtin_amdgcn_mfma_f32_32x32x16_bf16(ah, bh, acc, 0, 0, 0);
    acc = __builtin_amdgcn_mfma_f32_32x32x16_bf16(al, bh, acc, 0, 0, 0);
    acc = __builtin_amdgcn_mfma_f32_32x32x16_bf16(ah, bl, acc, 0, 0, 0);
  }
  #pragma unroll
  for (int r = 0; r < 16; ++r) {
    int mloc = (r & 3) + 8 * (r >> 2) + 4 * hh;
    P[(size_t)(row0 + mloc) * HIDDEN + col0 + n0 + l31] = acc[r];
  }
}

// -------------------------------------- per-batch 2048x2048 bf16 transpose (V -> V^T)
__global__ __launch_bounds__(256) void transpose_v(
    const ushort* __restrict__ S, ushort* __restrict__ D) {
  const int b = blockIdx.z;
  const int r0 = blockIdx.y * 32, c0 = blockIdx.x * 32;
  __shared__ ushort tile[32][33];
  const int t = threadIdx.x;
  const int r = t >> 3, cs = (t & 7) * 4;
  const ushort* Sb = S + (size_t)b * SEQ * HIDDEN;
  ushort* Db = D + (size_t)b * SEQ * HIDDEN;
  ushort4 v = *(const ushort4*)&Sb[(size_t)(r0 + r) * HIDDEN + c0 + cs];
  tile[r][cs] = v.x; tile[r][cs + 1] = v.y; tile[r][cs + 2] = v.z; tile[r][cs + 3] = v.w;
  __syncthreads();
  ushort4 o;
  o.x = tile[cs + 0][r]; o.y = tile[cs + 1][r];
  o.z = tile[cs + 2][r]; o.w = tile[cs + 3][r];
  *(ushort4*)&Db[(size_t)(c0 + r) * SEQ + r0 + cs] = o;
}

// ----------------------------------------------------------- MFMA flash attention
// R7 body; epilogue now writes AO as bf16 hi/lo planes (for the MFMA O-path).
#define BQ 128
#define BK 64
#define KSTR 136
#define VSTR 72

__device__ inline unsigned pkbf(float a, float b) {
  __hip_bfloat162 h2 = __float22bfloat162_rn(make_float2(a, b));
  union { __hip_bfloat162 h; unsigned u; } cv; cv.h = h2; return cv.u;
}

__global__ __launch_bounds__(256, 2) void attn_mfma(
    const ushort* __restrict__ Qg, const ushort* __restrict__ Kg,
    const ushort* __restrict__ Vt, ushort* __restrict__ Oh,
    ushort* __restrict__ Ol) {
  __shared__ __align__(16) union SM {
    ushort q[BQ][KSTR];
    struct { ushort k[BK][KSTR]; ushort v[HDIM][VSTR]; } kv[2];
  } sm;
  const int t = threadIdx.x;
  const int bh = blockIdx.x & 31;
  const int qt = blockIdx.x >> 5;
  const int b = bh >> 4, h = bh & 15;
  const int q0 = qt * BQ;
  const int lane = t & 63;
  const int w = t >> 6;
  const int l31 = lane & 31;
  const int hh = lane >> 5;
  const bool hi = (hh != 0);
  const float SC2 = 0.08838834764831845f * 1.4426950408889634f;

  const int sk_key = t >> 4;
  const int sk_d0 = (t & 15) * 8;
  const int sv_d = t >> 3;
  const int sv_k = (t & 7) * 8;
  const size_t kbase = ((size_t)(b * SEQ)) * HIDDEN + h * HDIM;
  const size_t vbase = ((size_t)(b * SEQ + h * HDIM)) * SEQ;

  {
    const size_t gbase = ((size_t)(b * SEQ + q0)) * HIDDEN + h * HDIM;
    for (int p = 0; p < 8; ++p) {
      int row = p * 16 + sk_key;
      uint4 v = *(const uint4*)&Qg[gbase + (size_t)row * HIDDEN + sk_d0];
      *(uint4*)&sm.q[row][sk_d0] = v;
    }
  }
  __syncthreads();
  bf16x8 Qf[8];
  {
    const int qrow = w * 32 + l31;
    #pragma unroll
    for (int ks = 0; ks < 8; ++ks)
      Qf[ks] = *(const bf16x8*)&sm.q[qrow][ks * 16 + 8 * hh];
  }
  __syncthreads();

  float mrow = -1e30f, lsum = 0.0f;
  f32x16 Ot[4];
  #pragma unroll
  for (int i = 0; i < 4; ++i)
    #pragma unroll
    for (int j = 0; j < 16; ++j) Ot[i][j] = 0.0f;

  uint4 kp[4], vp[4];
  {
    const size_t gb = kbase;
    #pragma unroll
    for (int p = 0; p < 4; ++p)
      kp[p] = *(const uint4*)&Kg[gb + (size_t)(p * 16 + sk_key) * HIDDEN + sk_d0];
    #pragma unroll
    for (int p = 0; p < 4; ++p)
      vp[p] = *(const uint4*)&Vt[vbase + (size_t)(p * 32 + sv_d) * SEQ + sv_k];
    #pragma unroll
    for (int p = 0; p < 4; ++p)
      *(uint4*)&sm.kv[0].k[p * 16 + sk_key][sk_d0] = kp[p];
    #pragma unroll
    for (int p = 0; p < 4; ++p)
      *(uint4*)&sm.kv[0].v[p * 32 + sv_d][sv_k] = vp[p];
  }
  __syncthreads();

  for (int ci = 0; ci < 32; ++ci) {
    {
      const int cn = (ci < 31) ? ci + 1 : 31;
      const size_t gb = kbase + (size_t)(cn * BK) * HIDDEN;
      #pragma unroll
      for (int p = 0; p < 4; ++p)
        kp[p] = *(const uint4*)&Kg[gb + (size_t)(p * 16 + sk_key) * HIDDEN + sk_d0];
      const size_t vb = vbase + cn * BK;
      #pragma unroll
      for (int p = 0; p < 4; ++p)
        vp[p] = *(const uint4*)&Vt[vb + (size_t)(p * 32 + sv_d) * SEQ + sv_k];
    }
    const int cb = ci & 1;

    f32x16 C0, C1;
    #pragma unroll
    for (int j = 0; j < 16; ++j) { C0[j] = 0.0f; C1[j] = 0.0f; }
    #pragma unroll
    for (int ks = 0; ks < 8; ++ks) {
      bf16x8 a0 = *(const bf16x8*)&sm.kv[cb].k[l31][ks * 16 + 8 * hh];
      bf16x8 a1 = *(const bf16x8*)&sm.kv[cb].k[32 + l31][ks * 16 + 8 * hh];
      C0 = __builtin_amdgcn_mfma_f32_32x32x16_bf16(a0, Qf[ks], C0, 0, 0, 0);
      C1 = __builtin_amdgcn_mfma_f32_32x32x16_bf16(a1, Qf[ks], C1, 0, 0, 0);
    }

    float mxr = -1e30f;
    #pragma unroll
    for (int j = 0; j < 16; ++j) mxr = fmaxf(mxr, fmaxf(C0[j], C1[j]));
    mxr = fmaxf(mxr, __shfl_xor(mxr, 32));
    const float mnew = fmaxf(mrow, mxr * SC2);
    const float alpha = exp2f(mrow - mnew);
    float ssum = 0.0f;
    #pragma unroll
    for (int j = 0; j < 16; ++j) {
      float e0 = exp2f(fmaf(C0[j], SC2, -mnew));
      float e1 = exp2f(fmaf(C1[j], SC2, -mnew));
      C0[j] = e0; C1[j] = e1;
      ssum += e0 + e1;
    }
    ssum += __shfl_xor(ssum, 32);
    lsum = lsum * alpha + ssum;
    mrow = mnew;
    #pragma unroll
    for (int i = 0; i < 4; ++i)
      #pragma unroll
      for (int j = 0; j < 16; ++j) Ot[i][j] *= alpha;

    #pragma unroll
    for (int st = 0; st < 4; ++st) {
      const int eb = 8 * (st & 1);
      float o0, o1, o2, o3, g0, g1, g2, g3;
      if (st < 2) {
        o0 = hi ? C0[eb + 4] : C0[eb + 0]; o1 = hi ? C0[eb + 5] : C0[eb + 1];
        o2 = hi ? C0[eb + 6] : C0[eb + 2]; o3 = hi ? C0[eb + 7] : C0[eb + 3];
        g0 = hi ? C0[eb + 0] : C0[eb + 4]; g1 = hi ? C0[eb + 1] : C0[eb + 5];
        g2 = hi ? C0[eb + 2] : C0[eb + 6]; g3 = hi ? C0[eb + 3] : C0[eb + 7];
      } else {
        o0 = hi ? C1[eb + 4] : C1[eb + 0]; o1 = hi ? C1[eb + 5] : C1[eb + 1];
        o2 = hi ? C1[eb + 6] : C1[eb + 2]; o3 = hi ? C1[eb + 7] : C1[eb + 3];
        g0 = hi ? C1[eb + 0] : C1[eb + 4]; g1 = hi ? C1[eb + 1] : C1[eb + 5];
        g2 = hi ? C1[eb + 2] : C1[eb + 6]; g3 = hi ? C1[eb + 3] : C1[eb + 7];
      }
      unsigned so0 = pkbf(o0, o1), so1 = pkbf(o2, o3);
      unsigned sp0 = pkbf(g0, g1), sp1 = pkbf(g2, g3);
      unsigned r0 = (unsigned)__shfl_xor((int)sp0, 32);
      unsigned r1 = (unsigned)__shfl_xor((int)sp1, 32);
      union { unsigned u[4]; bf16x8 v; } cv;
      cv.u[0] = hi ? r0 : so0;
      cv.u[1] = hi ? r1 : so1;
      cv.u[2] = hi ? so0 : r0;
      cv.u[3] = hi ? so1 : r1;
      #pragma unroll
      for (int mt = 0; mt < 4; ++mt) {
        bf16x8 a2 = *(const bf16x8*)&sm.kv[cb].v[mt * 32 + l31][st * 16 + 8 * hh];
        Ot[mt] = __builtin_amdgcn_mfma_f32_32x32x16_bf16(a2, cv.v, Ot[mt], 0, 0, 0);
      }
    }

    {
      const int nb = cb ^ 1;
      #pragma unroll
      for (int p = 0; p < 4; ++p)
        *(uint4*)&sm.kv[nb].k[p * 16 + sk_key][sk_d0] = kp[p];
      #pragma unroll
      for (int p = 0; p < 4; ++p)
        *(uint4*)&sm.kv[nb].v[p * 32 + sv_d][sv_k] = vp[p];
    }
    __syncthreads();
  }

  // ---- epilogue: normalized AO as bf16 hi/lo planes
  const float inv = 1.0f / lsum;
  const int qrow = q0 + w * 32 + l31;
  const size_t ob = ((size_t)(b * SEQ + qrow)) * HIDDEN + h * HDIM;
  #pragma unroll
  for (int mt = 0; mt < 4; ++mt)
    #pragma unroll
    for (int g = 0; g < 4; ++g) {
      ushort4 hs, ls;
      split_bf(Ot[mt][4 * g + 0] * inv, hs.x, ls.x);
      split_bf(Ot[mt][4 * g + 1] * inv, hs.y, ls.y);
      split_bf(Ot[mt][4 * g + 2] * inv, hs.z, ls.z);
      split_bf(Ot[mt][4 * g + 3] * inv, hs.w, ls.w);
      const size_t off = ob + mt * 32 + 8 * g + 4 * hh;
      *(ushort4*)&Oh[off] = hs;
      *(ushort4*)&Ol[off] = ls;
    }
}

// -------------------------------------------------------------------------- launcher
extern "C" void kernel_launch(void* const* d_in, const int* in_sizes, int n_in,
                              void* d_out, int out_size, void* d_ws, size_t ws_size,
                              hipStream_t stream) {
  (void)in_sizes; (void)n_in; (void)out_size; (void)ws_size;
  const float* X       = (const float*)d_in[0];
  const float* basis_q = (const float*)d_in[1];
  const float* phase_q = (const float*)d_in[2];
  const float* amp_q   = (const float*)d_in[3];
  const float* basis_k = (const float*)d_in[4];
  const float* phase_k = (const float*)d_in[5];
  const float* amp_k   = (const float*)d_in[6];
  const float* basis_v = (const float*)d_in[7];
  const float* phase_v = (const float*)d_in[8];
  const float* amp_v   = (const float*)d_in[9];
  const float* basis_o = (const float*)d_in[10];
  const float* phase_o = (const float*)d_in[11];
  const float* amp_o   = (const float*)d_in[12];

  const size_t WN = (size_t)HIDDEN * HARM;   // 131072

  char* p = (char*)d_ws;
  ushort* Xhi = (ushort*)p; p += PN * 2;
  ushort* Xlo = (ushort*)p; p += PN * 2;
  ushort* Bhi = (ushort*)p; p += 4 * WN * 2;
  ushort* Blo = (ushort*)p; p += 4 * WN * 2;
  ushort* Whi = (ushort*)p; p += 4 * WN * 2;
  ushort* Wlo = (ushort*)p; p += 4 * WN * 2;
  float* Rqp = (float*)p; p += (size_t)4 * RN * 4;
  float* Rkp = (float*)p; p += (size_t)4 * RN * 4;
  float* Rvp = (float*)p; p += (size_t)4 * RN * 4;
  float* Rop = (float*)p; p += (size_t)4 * RN * 4;
  __hip_bfloat16* Qb = (__hip_bfloat16*)p; p += PN * 2;
  __hip_bfloat16* Kb = (__hip_bfloat16*)p; p += PN * 2;
  __hip_bfloat16* Vb = (__hip_bfloat16*)p; p += PN * 2;
  __hip_bfloat16* VtB = (__hip_bfloat16*)p; p += PN * 2;
  ushort* AOh = (ushort*)p; p += PN * 2;
  ushort* AOl = (ushort*)p; p += PN * 2;
  float* out = (float*)d_out;

  cast_x<<<8192, 256, 0, stream>>>(X, Xhi, Xlo);
  wt2_kernel<<<2048, 256, 0, stream>>>(phase_q, amp_q, phase_k, amp_k,
                                       phase_v, amp_v, phase_o, amp_o,
                                       Whi, Wlo);
  cast_basis<<<dim3(128, 4), 256, 0, stream>>>(basis_q, basis_k, basis_v, basis_o,
                                               Bhi, Blo);

  gemm_res<<<dim3(64, 4, 3), 256, 0, stream>>>(Xhi, Xlo, Bhi, Blo, Rqp, Rkp, Rvp);

  gemm_proj<<<dim3(128, 16, 3), 256, 0, stream>>>(
      Rqp, Rkp, Rvp, Whi, Wlo, (ushort*)Qb, (ushort*)Kb, (ushort*)Vb);

  transpose_v<<<dim3(HIDDEN / 32, SEQ / 32, BATCH), 256, 0, stream>>>(
      (const ushort*)Vb, (ushort*)VtB);

  attn_mfma<<<dim3((SEQ / BQ) * 32), 256, 0, stream>>>(
      (const ushort*)Qb, (const ushort*)Kb, (const ushort*)VtB, AOh, AOl);

  // O-path: resonance on merged AO (hi/lo), basis_o = plane 3
  gemm_res<<<dim3(64, 4, 1), 256, 0, stream>>>(
      AOh, AOl, Bhi + 3 * WN, Blo + 3 * WN, Rop, Rop, Rop);

  gemm_proj_f32<<<dim3(128, 16), 256, 0, stream>>>(
      Rop, Whi + 3 * WN, Wlo + 3 * WN, out);
}

// Round 10
// 275.623 us; speedup vs baseline: 1.5511x; 1.0400x over previous
//
#include <hip/hip_runtime.h>
#include <hip/hip_bf16.h>
#include <math.h>

#define HIDDEN 2048
#define HARM   64
#define NHEADS 16
#define HDIM   128
#define SEQ    2048
#define BATCH  2
#define ROWS   (BATCH*SEQ)   // 4096
#define RN     (ROWS*HARM)   // 262144 (one K-chunk partial plane)
#define PN     ((size_t)ROWS*HIDDEN)  // 8388608

using bf16x8 = __attribute__((ext_vector_type(8))) short;
using f32x16 = __attribute__((ext_vector_type(16))) float;

// hi/lo double-bf16 split: a ~= hi + lo with ~16-bit effective mantissa
__device__ inline void split_bf(float a, ushort& hi, ushort& lo) {
  __hip_bfloat16 h = __float2bfloat16(a);
  float hf = __bfloat162float(h);
  __hip_bfloat16 l = __float2bfloat16(a - hf);
  union { __hip_bfloat16 b; ushort u; } c1, c2;
  c1.b = h; c2.b = l;
  hi = c1.u; lo = c2.u;
}

// ---------------- fused prep: cast X (blocks 0..8191), w=amp*cos(phase) hi/lo
// (blocks 8192..10239), cast basis q/k/v/o hi/lo (blocks 10240..10751)
__global__ __launch_bounds__(256) void prep(
    const float* __restrict__ X,
    const float* __restrict__ pq, const float* __restrict__ aq,
    const float* __restrict__ pk, const float* __restrict__ ak,
    const float* __restrict__ pv, const float* __restrict__ av,
    const float* __restrict__ po, const float* __restrict__ ao,
    const float* __restrict__ bq, const float* __restrict__ bk,
    const float* __restrict__ bv, const float* __restrict__ bo,
    ushort* __restrict__ Xh, ushort* __restrict__ Xl,
    ushort* __restrict__ Wh, ushort* __restrict__ Wl,
    ushort* __restrict__ Bh, ushort* __restrict__ Bl) {
  const int bid = blockIdx.x;
  const int t = threadIdx.x;
  if (bid < 8192) {
    size_t i = ((size_t)bid * 256 + t) * 4;
    float4 v = *(const float4*)&X[i];
    ushort4 h, l;
    split_bf(v.x, h.x, l.x); split_bf(v.y, h.y, l.y);
    split_bf(v.z, h.z, l.z); split_bf(v.w, h.w, l.w);
    *(ushort4*)&Xh[i] = h;
    *(ushort4*)&Xl[i] = l;
  } else if (bid < 10240) {
    int i = (bid - 8192) * 256 + t;
    const int N = HIDDEN * HARM;
    int set = i / N, j = i - set * N;
    const float* p = (set == 0) ? pq : (set == 1) ? pk : (set == 2) ? pv : po;
    const float* a = (set == 0) ? aq : (set == 1) ? ak : (set == 2) ? av : ao;
    float wv = a[j] * cosf(p[j]);
    ushort h, l;
    split_bf(wv, h, l);
    size_t o = (size_t)set * N + j;
    Wh[o] = h; Wl[o] = l;
  } else {
    int idx = bid - 10240;          // 512 blocks = 128 x 4
    int z = idx >> 7, xb = idx & 127;
    const float* S = (z == 0) ? bq : (z == 1) ? bk : (z == 2) ? bv : bo;
    size_t i = ((size_t)xb * 256 + t) * 4;
    float4 v = *(const float4*)&S[i];
    ushort4 h, l;
    split_bf(v.x, h.x, l.x); split_bf(v.y, h.y, l.y);
    split_bf(v.z, h.z, l.z); split_bf(v.w, h.w, l.w);
    size_t o = (size_t)z * HARM * HIDDEN + i;
    *(ushort4*)&Bh[o] = h;
    *(ushort4*)&Bl[o] = l;
  }
}

// --------------- MFMA resonance (double-bf16): Rp[kc][M][64] = X * basis^T
__global__ __launch_bounds__(256) void gemm_res(
    const ushort* __restrict__ Xh, const ushort* __restrict__ Xl,
    const ushort* __restrict__ Bh, const ushort* __restrict__ Bl,
    float* __restrict__ R0, float* __restrict__ R1, float* __restrict__ R2) {
  const int z = blockIdx.z;
  const ushort* Bhz = Bh + (size_t)z * HARM * HIDDEN;
  const ushort* Blz = Bl + (size_t)z * HARM * HIDDEN;
  float* Rp = (z == 0) ? R0 : (z == 1) ? R1 : R2;
  const int row0 = blockIdx.x * 64;
  const int kc = blockIdx.y;
  __shared__ __align__(16) ushort Xs[2][64][72];
  __shared__ __align__(16) ushort Bs[2][64][72];
  const int t = threadIdx.x;
  const int lane = t & 63, w = t >> 6;
  const int l31 = lane & 31, hh = lane >> 5;
  const int m0 = (w & 1) * 32, n0 = (w >> 1) * 32;
  const int srow = t >> 2;
  const int sc = (t & 3) * 16;
  f32x16 acc;
  #pragma unroll
  for (int j = 0; j < 16; ++j) acc[j] = 0.0f;

  const int kbase = kc * 512;
  for (int k0 = kbase; k0 < kbase + 512; k0 += 64) {
    const size_t xo = (size_t)(row0 + srow) * HIDDEN + k0 + sc;
    const size_t bo = (size_t)srow * HIDDEN + k0 + sc;
    *(uint4*)&Xs[0][srow][sc]     = *(const uint4*)&Xh[xo];
    *(uint4*)&Xs[0][srow][sc + 8] = *(const uint4*)&Xh[xo + 8];
    *(uint4*)&Xs[1][srow][sc]     = *(const uint4*)&Xl[xo];
    *(uint4*)&Xs[1][srow][sc + 8] = *(const uint4*)&Xl[xo + 8];
    *(uint4*)&Bs[0][srow][sc]     = *(const uint4*)&Bhz[bo];
    *(uint4*)&Bs[0][srow][sc + 8] = *(const uint4*)&Bhz[bo + 8];
    *(uint4*)&Bs[1][srow][sc]     = *(const uint4*)&Blz[bo];
    *(uint4*)&Bs[1][srow][sc + 8] = *(const uint4*)&Blz[bo + 8];
    __syncthreads();
    #pragma unroll
    for (int ks = 0; ks < 4; ++ks) {
      bf16x8 ah = *(const bf16x8*)&Xs[0][m0 + l31][ks * 16 + 8 * hh];
      bf16x8 al = *(const bf16x8*)&Xs[1][m0 + l31][ks * 16 + 8 * hh];
      bf16x8 bh = *(const bf16x8*)&Bs[0][n0 + l31][ks * 16 + 8 * hh];
      bf16x8 bl = *(const bf16x8*)&Bs[1][n0 + l31][ks * 16 + 8 * hh];
      acc = __builtin_amdgcn_mfma_f32_32x32x16_bf16(ah, bh, acc, 0, 0, 0);
      acc = __builtin_amdgcn_mfma_f32_32x32x16_bf16(al, bh, acc, 0, 0, 0);
      acc = __builtin_amdgcn_mfma_f32_32x32x16_bf16(ah, bl, acc, 0, 0, 0);
    }
    __syncthreads();
  }
  float* out = Rp + (size_t)kc * ROWS * HARM;
  #pragma unroll
  for (int r = 0; r < 16; ++r) {
    int mloc = (r & 3) + 8 * (r >> 2) + 4 * hh;
    out[(size_t)(row0 + m0 + mloc) * HARM + n0 + l31] = acc[r];
  }
}

// --------------- MFMA projection (double-bf16): P = (sum_kc Rp) * W^T, bf16 out
// z=0 -> Qb, z=1 -> Kb, z=2 -> V written DIRECTLY TRANSPOSED into VtB via an LDS
// column tile (replaces the separate transpose_v kernel).
__global__ __launch_bounds__(256) void gemm_proj(
    const float* __restrict__ Rp0, const float* __restrict__ Rp1,
    const float* __restrict__ Rp2,
    const ushort* __restrict__ Wh, const ushort* __restrict__ Wl,
    ushort* __restrict__ P0, ushort* __restrict__ P1, ushort* __restrict__ Vt) {
  const int z = blockIdx.z;
  const float* Rp = (z == 0) ? Rp0 : (z == 1) ? Rp1 : Rp2;
  const ushort* Whz = Wh + (size_t)z * HIDDEN * HARM;
  const ushort* Wlz = Wl + (size_t)z * HIDDEN * HARM;
  const int row0 = blockIdx.x * 32;
  const int col0 = blockIdx.y * 128;
  __shared__ __align__(16) union PSM {
    struct { ushort Rs[2][32][72]; ushort Ws[2][128][72]; } s;
    ushort ct[128][36];   // [local col][local row] for the V-transpose epilogue
  } sm;
  const int t = threadIdx.x;
  const int lane = t & 63, w = t >> 6;
  const int l31 = lane & 31, hh = lane >> 5;
  {
    const int r = t >> 3, h0 = (t & 7) * 8;
    const size_t o = (size_t)(row0 + r) * HARM + h0;
    #pragma unroll
    for (int e = 0; e < 8; ++e) {
      float v = Rp[o + e] + Rp[RN + o + e] + Rp[2 * (size_t)RN + o + e] +
                Rp[3 * (size_t)RN + o + e];
      ushort hi, lo;
      split_bf(v, hi, lo);
      sm.s.Rs[0][r][h0 + e] = hi;
      sm.s.Rs[1][r][h0 + e] = lo;
    }
  }
  #pragma unroll
  for (int i = 0; i < 4; ++i) {
    int idx = t + i * 256;
    int o = idx >> 3, c8 = (idx & 7) * 8;
    const size_t go = (size_t)(col0 + o) * HARM + c8;
    *(uint4*)&sm.s.Ws[0][o][c8] = *(const uint4*)&Whz[go];
    *(uint4*)&sm.s.Ws[1][o][c8] = *(const uint4*)&Wlz[go];
  }
  __syncthreads();
  const int n0 = w * 32;
  f32x16 acc;
  #pragma unroll
  for (int j = 0; j < 16; ++j) acc[j] = 0.0f;
  #pragma unroll
  for (int ks = 0; ks < 4; ++ks) {
    bf16x8 ah = *(const bf16x8*)&sm.s.Rs[0][l31][ks * 16 + 8 * hh];
    bf16x8 al = *(const bf16x8*)&sm.s.Rs[1][l31][ks * 16 + 8 * hh];
    bf16x8 bh = *(const bf16x8*)&sm.s.Ws[0][n0 + l31][ks * 16 + 8 * hh];
    bf16x8 bl = *(const bf16x8*)&sm.s.Ws[1][n0 + l31][ks * 16 + 8 * hh];
    acc = __builtin_amdgcn_mfma_f32_32x32x16_bf16(ah, bh, acc, 0, 0, 0);
    acc = __builtin_amdgcn_mfma_f32_32x32x16_bf16(al, bh, acc, 0, 0, 0);
    acc = __builtin_amdgcn_mfma_f32_32x32x16_bf16(ah, bl, acc, 0, 0, 0);
  }
  if (z < 2) {
    ushort* P = (z == 0) ? P0 : P1;
    #pragma unroll
    for (int r = 0; r < 16; ++r) {
      int mloc = (r & 3) + 8 * (r >> 2) + 4 * hh;
      union { __hip_bfloat16 b; ushort u; } cv;
      cv.b = __float2bfloat16(acc[r]);
      P[(size_t)(row0 + mloc) * HIDDEN + col0 + n0 + l31] = cv.u;
    }
  } else {
    // V: route through LDS [col][row], store transposed with full 64B lines
    __syncthreads();   // staging reads finished everywhere before aliasing
    #pragma unroll
    for (int r = 0; r < 16; ++r) {
      int mloc = (r & 3) + 8 * (r >> 2) + 4 * hh;
      union { __hip_bfloat16 b; ushort u; } cv;
      cv.b = __float2bfloat16(acc[r]);
      sm.ct[n0 + l31][mloc] = cv.u;
    }
    __syncthreads();
    if (t < 128) {
      const int batch = row0 >> 11;
      const int tok0 = row0 & 2047;
      ushort* dst = Vt + (size_t)batch * SEQ * HIDDEN +
                    (size_t)(col0 + t) * SEQ + tok0;
      #pragma unroll
      for (int j = 0; j < 4; ++j)
        *(uint4*)&dst[j * 8] = *(const uint4*)&sm.ct[t][j * 8];
    }
  }
}

// --------------- MFMA final projection (double-bf16, fp32 out), grid (128, 16)
__global__ __launch_bounds__(256) void gemm_proj_f32(
    const float* __restrict__ Rp,
    const ushort* __restrict__ Whz, const ushort* __restrict__ Wlz,
    float* __restrict__ P) {
  const int row0 = blockIdx.x * 32;
  const int col0 = blockIdx.y * 128;
  __shared__ __align__(16) ushort Rs[2][32][72];
  __shared__ __align__(16) ushort Ws[2][128][72];
  const int t = threadIdx.x;
  const int lane = t & 63, w = t >> 6;
  const int l31 = lane & 31, hh = lane >> 5;
  {
    const int r = t >> 3, h0 = (t & 7) * 8;
    const size_t o = (size_t)(row0 + r) * HARM + h0;
    #pragma unroll
    for (int e = 0; e < 8; ++e) {
      float v = Rp[o + e] + Rp[RN + o + e] + Rp[2 * (size_t)RN + o + e] +
                Rp[3 * (size_t)RN + o + e];
      ushort hi, lo;
      split_bf(v, hi, lo);
      Rs[0][r][h0 + e] = hi;
      Rs[1][r][h0 + e] = lo;
    }
  }
  #pragma unroll
  for (int i = 0; i < 4; ++i) {
    int idx = t + i * 256;
    int o = idx >> 3, c8 = (idx & 7) * 8;
    const size_t go = (size_t)(col0 + o) * HARM + c8;
    *(uint4*)&Ws[0][o][c8] = *(const uint4*)&Whz[go];
    *(uint4*)&Ws[1][o][c8] = *(const uint4*)&Wlz[go];
  }
  __syncthreads();
  const int n0 = w * 32;
  f32x16 acc;
  #pragma unroll
  for (int j = 0; j < 16; ++j) acc[j] = 0.0f;
  #pragma unroll
  for (int ks = 0; ks < 4; ++ks) {
    bf16x8 ah = *(const bf16x8*)&Rs[0][l31][ks * 16 + 8 * hh];
    bf16x8 al = *(const bf16x8*)&Rs[1][l31][ks * 16 + 8 * hh];
    bf16x8 bh = *(const bf16x8*)&Ws[0][n0 + l31][ks * 16 + 8 * hh];
    bf16x8 bl = *(const bf16x8*)&Ws[1][n0 + l31][ks * 16 + 8 * hh];
    acc = __builtin_amdgcn_mfma_f32_32x32x16_bf16(ah, bh, acc, 0, 0, 0);
    acc = __builtin_amdgcn_mfma_f32_32x32x16_bf16(al, bh, acc, 0, 0, 0);
    acc = __builtin_amdgcn_mfma_f32_32x32x16_bf16(ah, bl, acc, 0, 0, 0);
  }
  #pragma unroll
  for (int r = 0; r < 16; ++r) {
    int mloc = (r & 3) + 8 * (r >> 2) + 4 * hh;
    P[(size_t)(row0 + mloc) * HIDDEN + col0 + n0 + l31] = acc[r];
  }
}

// ----------------------------------------------------------- MFMA flash attention
// R7 body; epilogue writes AO as bf16 hi/lo planes. UNCHANGED (control).
#define BQ 128
#define BK 64
#define KSTR 136
#define VSTR 72

__device__ inline unsigned pkbf(float a, float b) {
  __hip_bfloat162 h2 = __float22bfloat162_rn(make_float2(a, b));
  union { __hip_bfloat162 h; unsigned u; } cv; cv.h = h2; return cv.u;
}

__global__ __launch_bounds__(256, 2) void attn_mfma(
    const ushort* __restrict__ Qg, const ushort* __restrict__ Kg,
    const ushort* __restrict__ Vt, ushort* __restrict__ Oh,
    ushort* __restrict__ Ol) {
  __shared__ __align__(16) union SM {
    ushort q[BQ][KSTR];
    struct { ushort k[BK][KSTR]; ushort v[HDIM][VSTR]; } kv[2];
  } sm;
  const int t = threadIdx.x;
  const int bh = blockIdx.x & 31;
  const int qt = blockIdx.x >> 5;
  const int b = bh >> 4, h = bh & 15;
  const int q0 = qt * BQ;
  const int lane = t & 63;
  const int w = t >> 6;
  const int l31 = lane & 31;
  const int hh = lane >> 5;
  const bool hi = (hh != 0);
  const float SC2 = 0.08838834764831845f * 1.4426950408889634f;

  const int sk_key = t >> 4;
  const int sk_d0 = (t & 15) * 8;
  const int sv_d = t >> 3;
  const int sv_k = (t & 7) * 8;
  const size_t kbase = ((size_t)(b * SEQ)) * HIDDEN + h * HDIM;
  const size_t vbase = ((size_t)(b * SEQ + h * HDIM)) * SEQ;

  {
    const size_t gbase = ((size_t)(b * SEQ + q0)) * HIDDEN + h * HDIM;
    for (int p = 0; p < 8; ++p) {
      int row = p * 16 + sk_key;
      uint4 v = *(const uint4*)&Qg[gbase + (size_t)row * HIDDEN + sk_d0];
      *(uint4*)&sm.q[row][sk_d0] = v;
    }
  }
  __syncthreads();
  bf16x8 Qf[8];
  {
    const int qrow = w * 32 + l31;
    #pragma unroll
    for (int ks = 0; ks < 8; ++ks)
      Qf[ks] = *(const bf16x8*)&sm.q[qrow][ks * 16 + 8 * hh];
  }
  __syncthreads();

  float mrow = -1e30f, lsum = 0.0f;
  f32x16 Ot[4];
  #pragma unroll
  for (int i = 0; i < 4; ++i)
    #pragma unroll
    for (int j = 0; j < 16; ++j) Ot[i][j] = 0.0f;

  uint4 kp[4], vp[4];
  {
    const size_t gb = kbase;
    #pragma unroll
    for (int p = 0; p < 4; ++p)
      kp[p] = *(const uint4*)&Kg[gb + (size_t)(p * 16 + sk_key) * HIDDEN + sk_d0];
    #pragma unroll
    for (int p = 0; p < 4; ++p)
      vp[p] = *(const uint4*)&Vt[vbase + (size_t)(p * 32 + sv_d) * SEQ + sv_k];
    #pragma unroll
    for (int p = 0; p < 4; ++p)
      *(uint4*)&sm.kv[0].k[p * 16 + sk_key][sk_d0] = kp[p];
    #pragma unroll
    for (int p = 0; p < 4; ++p)
      *(uint4*)&sm.kv[0].v[p * 32 + sv_d][sv_k] = vp[p];
  }
  __syncthreads();

  for (int ci = 0; ci < 32; ++ci) {
    {
      const int cn = (ci < 31) ? ci + 1 : 31;
      const size_t gb = kbase + (size_t)(cn * BK) * HIDDEN;
      #pragma unroll
      for (int p = 0; p < 4; ++p)
        kp[p] = *(const uint4*)&Kg[gb + (size_t)(p * 16 + sk_key) * HIDDEN + sk_d0];
      const size_t vb = vbase + cn * BK;
      #pragma unroll
      for (int p = 0; p < 4; ++p)
        vp[p] = *(const uint4*)&Vt[vb + (size_t)(p * 32 + sv_d) * SEQ + sv_k];
    }
    const int cb = ci & 1;

    f32x16 C0, C1;
    #pragma unroll
    for (int j = 0; j < 16; ++j) { C0[j] = 0.0f; C1[j] = 0.0f; }
    #pragma unroll
    for (int ks = 0; ks < 8; ++ks) {
      bf16x8 a0 = *(const bf16x8*)&sm.kv[cb].k[l31][ks * 16 + 8 * hh];
      bf16x8 a1 = *(const bf16x8*)&sm.kv[cb].k[32 + l31][ks * 16 + 8 * hh];
      C0 = __builtin_amdgcn_mfma_f32_32x32x16_bf16(a0, Qf[ks], C0, 0, 0, 0);
      C1 = __builtin_amdgcn_mfma_f32_32x32x16_bf16(a1, Qf[ks], C1, 0, 0, 0);
    }

    float mxr = -1e30f;
    #pragma unroll
    for (int j = 0; j < 16; ++j) mxr = fmaxf(mxr, fmaxf(C0[j], C1[j]));
    mxr = fmaxf(mxr, __shfl_xor(mxr, 32));
    const float mnew = fmaxf(mrow, mxr * SC2);
    const float alpha = exp2f(mrow - mnew);
    float ssum = 0.0f;
    #pragma unroll
    for (int j = 0; j < 16; ++j) {
      float e0 = exp2f(fmaf(C0[j], SC2, -mnew));
      float e1 = exp2f(fmaf(C1[j], SC2, -mnew));
      C0[j] = e0; C1[j] = e1;
      ssum += e0 + e1;
    }
    ssum += __shfl_xor(ssum, 32);
    lsum = lsum * alpha + ssum;
    mrow = mnew;
    #pragma unroll
    for (int i = 0; i < 4; ++i)
      #pragma unroll
      for (int j = 0; j < 16; ++j) Ot[i][j] *= alpha;

    #pragma unroll
    for (int st = 0; st < 4; ++st) {
      const int eb = 8 * (st & 1);
      float o0, o1, o2, o3, g0, g1, g2, g3;
      if (st < 2) {
        o0 = hi ? C0[eb + 4] : C0[eb + 0]; o1 = hi ? C0[eb + 5] : C0[eb + 1];
        o2 = hi ? C0[eb + 6] : C0[eb + 2]; o3 = hi ? C0[eb + 7] : C0[eb + 3];
        g0 = hi ? C0[eb + 0] : C0[eb + 4]; g1 = hi ? C0[eb + 1] : C0[eb + 5];
        g2 = hi ? C0[eb + 2] : C0[eb + 6]; g3 = hi ? C0[eb + 3] : C0[eb + 7];
      } else {
        o0 = hi ? C1[eb + 4] : C1[eb + 0]; o1 = hi ? C1[eb + 5] : C1[eb + 1];
        o2 = hi ? C1[eb + 6] : C1[eb + 2]; o3 = hi ? C1[eb + 7] : C1[eb + 3];
        g0 = hi ? C1[eb + 0] : C1[eb + 4]; g1 = hi ? C1[eb + 1] : C1[eb + 5];
        g2 = hi ? C1[eb + 2] : C1[eb + 6]; g3 = hi ? C1[eb + 3] : C1[eb + 7];
      }
      unsigned so0 = pkbf(o0, o1), so1 = pkbf(o2, o3);
      unsigned sp0 = pkbf(g0, g1), sp1 = pkbf(g2, g3);
      unsigned r0 = (unsigned)__shfl_xor((int)sp0, 32);
      unsigned r1 = (unsigned)__shfl_xor((int)sp1, 32);
      union { unsigned u[4]; bf16x8 v; } cv;
      cv.u[0] = hi ? r0 : so0;
      cv.u[1] = hi ? r1 : so1;
      cv.u[2] = hi ? so0 : r0;
      cv.u[3] = hi ? so1 : r1;
      #pragma unroll
      for (int mt = 0; mt < 4; ++mt) {
        bf16x8 a2 = *(const bf16x8*)&sm.kv[cb].v[mt * 32 + l31][st * 16 + 8 * hh];
        Ot[mt] = __builtin_amdgcn_mfma_f32_32x32x16_bf16(a2, cv.v, Ot[mt], 0, 0, 0);
      }
    }

    {
      const int nb = cb ^ 1;
      #pragma unroll
      for (int p = 0; p < 4; ++p)
        *(uint4*)&sm.kv[nb].k[p * 16 + sk_key][sk_d0] = kp[p];
      #pragma unroll
      for (int p = 0; p < 4; ++p)
        *(uint4*)&sm.kv[nb].v[p * 32 + sv_d][sv_k] = vp[p];
    }
    __syncthreads();
  }

  // ---- epilogue: normalized AO as bf16 hi/lo planes
  const float inv = 1.0f / lsum;
  const int qrow = q0 + w * 32 + l31;
  const size_t ob = ((size_t)(b * SEQ + qrow)) * HIDDEN + h * HDIM;
  #pragma unroll
  for (int mt = 0; mt < 4; ++mt)
    #pragma unroll
    for (int g = 0; g < 4; ++g) {
      ushort4 hs, ls;
      split_bf(Ot[mt][4 * g + 0] * inv, hs.x, ls.x);
      split_bf(Ot[mt][4 * g + 1] * inv, hs.y, ls.y);
      split_bf(Ot[mt][4 * g + 2] * inv, hs.z, ls.z);
      split_bf(Ot[mt][4 * g + 3] * inv, hs.w, ls.w);
      const size_t off = ob + mt * 32 + 8 * g + 4 * hh;
      *(ushort4*)&Oh[off] = hs;
      *(ushort4*)&Ol[off] = ls;
    }
}

// -------------------------------------------------------------------------- launcher
extern "C" void kernel_launch(void* const* d_in, const int* in_sizes, int n_in,
                              void* d_out, int out_size, void* d_ws, size_t ws_size,
                              hipStream_t stream) {
  (void)in_sizes; (void)n_in; (void)out_size; (void)ws_size;
  const float* X       = (const float*)d_in[0];
  const float* basis_q = (const float*)d_in[1];
  const float* phase_q = (const float*)d_in[2];
  const float* amp_q   = (const float*)d_in[3];
  const float* basis_k = (const float*)d_in[4];
  const float* phase_k = (const float*)d_in[5];
  const float* amp_k   = (const float*)d_in[6];
  const float* basis_v = (const float*)d_in[7];
  const float* phase_v = (const float*)d_in[8];
  const float* amp_v   = (const float*)d_in[9];
  const float* basis_o = (const float*)d_in[10];
  const float* phase_o = (const float*)d_in[11];
  const float* amp_o   = (const float*)d_in[12];

  const size_t WN = (size_t)HIDDEN * HARM;   // 131072

  char* p = (char*)d_ws;
  ushort* Xhi = (ushort*)p; p += PN * 2;
  ushort* Xlo = (ushort*)p; p += PN * 2;
  ushort* Bhi = (ushort*)p; p += 4 * WN * 2;
  ushort* Blo = (ushort*)p; p += 4 * WN * 2;
  ushort* Whi = (ushort*)p; p += 4 * WN * 2;
  ushort* Wlo = (ushort*)p; p += 4 * WN * 2;
  float* Rqp = (float*)p; p += (size_t)4 * RN * 4;
  float* Rkp = (float*)p; p += (size_t)4 * RN * 4;
  float* Rvp = (float*)p; p += (size_t)4 * RN * 4;
  float* Rop = (float*)p; p += (size_t)4 * RN * 4;
  __hip_bfloat16* Qb = (__hip_bfloat16*)p; p += PN * 2;
  __hip_bfloat16* Kb = (__hip_bfloat16*)p; p += PN * 2;
  __hip_bfloat16* VtB = (__hip_bfloat16*)p; p += PN * 2;
  ushort* AOh = (ushort*)p; p += PN * 2;
  ushort* AOl = (ushort*)p; p += PN * 2;
  float* out = (float*)d_out;

  prep<<<10752, 256, 0, stream>>>(X,
                                  phase_q, amp_q, phase_k, amp_k,
                                  phase_v, amp_v, phase_o, amp_o,
                                  basis_q, basis_k, basis_v, basis_o,
                                  Xhi, Xlo, Whi, Wlo, Bhi, Blo);

  gemm_res<<<dim3(64, 4, 3), 256, 0, stream>>>(Xhi, Xlo, Bhi, Blo, Rqp, Rkp, Rvp);

  gemm_proj<<<dim3(128, 16, 3), 256, 0, stream>>>(
      Rqp, Rkp, Rvp, Whi, Wlo, (ushort*)Qb, (ushort*)Kb, (ushort*)VtB);

  attn_mfma<<<dim3((SEQ / BQ) * 32), 256, 0, stream>>>(
      (const ushort*)Qb, (const ushort*)Kb, (const ushort*)VtB, AOh, AOl);

  gemm_res<<<dim3(64, 4, 1), 256, 0, stream>>>(
      AOh, AOl, Bhi + 3 * WN, Blo + 3 * WN, Rop, Rop, Rop);

  gemm_proj_f32<<<dim3(128, 16), 256, 0, stream>>>(
      Rop, Whi + 3 * WN, Wlo + 3 * WN, out);
}